// Round 13
// baseline (916.517 us; speedup 1.0000x reference)
//
#include <hip/hip_runtime.h>
#include <hip/hip_bf16.h>
#include <math.h>

#define TAU 6.283185307179586f
#define NK 576                    // matrix dimension (K always exact: 18*32)
#define NPAD 640                  // padded row count (legacy layout; rows >=576 unused)
#define PLN ((size_t)NPAD * NK)   // elems per padded plane = 368640
#define SETSTR ((size_t)4 * PLN)  // elems per 4-plane split set
#define MAPSZ 102400              // 16*16*20*20
#define KOUT 416                  // padded K for output gemm (13*32)
#define XPL ((size_t)8192 * KOUT)
#define MPL ((size_t)4096 * KOUT)

typedef __attribute__((ext_vector_type(8))) short short8;
typedef __attribute__((ext_vector_type(4))) short short4v;
typedef __attribute__((ext_vector_type(4))) float f32x4;

__device__ inline void bsplit(float v, __hip_bfloat16& h, __hip_bfloat16& l) {
  h = __float2bfloat16(v);
  l = __float2bfloat16(v - __bfloat162float(h));
}
__device__ inline short braw(__hip_bfloat16 b) { return *reinterpret_cast<short*>(&b); }

__device__ inline void gld16(const void* g, const void* l) {
  __builtin_amdgcn_global_load_lds((const __attribute__((address_space(1))) unsigned*)g,
                                   (__attribute__((address_space(3))) unsigned*)l, 16, 0, 0);
}

#define MFMA16(a, b, c) __builtin_amdgcn_mfma_f32_16x16x32_bf16(a, b, c, 0, 0, 0)

// ---------------- Stage 1: signal -> spectrum ----------------
__device__ inline void dft24(const float2* in, float2* out, int t, float sgn, bool firstAxis) {
  int r = t / 24, c = t % 24;
  int kk = firstAxis ? r : c;
  float2 acc = make_float2(0.f, 0.f);
  for (int n = 0; n < 24; ++n) {
    float ang = sgn * (TAU / 24.f) * (float)((kk * n) % 24);
    float s, co;
    sincosf(ang, &s, &co);
    float2 v = firstAxis ? in[n * 24 + c] : in[r * 24 + n];
    acc.x += v.x * co - v.y * s;
    acc.y += v.x * s + v.y * co;
  }
  out[t] = acc;
}

__global__ void spectrum_kernel(const float* __restrict__ sig, float2* __restrict__ spec) {
  __shared__ float2 b0[576];
  __shared__ float2 b1[576];
  int f = blockIdx.x;
  int t = threadIdx.x;
  int r = t / 24, c = t % 24;
  b0[t] = make_float2(sig[f * 576 + t], 0.f);
  __syncthreads();
  dft24(b0, b1, t, -1.f, false); __syncthreads();
  dft24(b1, b0, t, -1.f, true);  __syncthreads();
  {
    int p2 = (r + 12) % 24 - 11;
    int q2 = (c + 12) % 24 - 11;
    float rr = (float)(1 + p2 * p2 + q2 * q2) * 5.f;
    float2 v = b0[t];
    b0[t] = make_float2(v.x / rr, v.y / rr);
  }
  __syncthreads();
  dft24(b0, b1, t, +1.f, false); __syncthreads();
  dft24(b1, b0, t, +1.f, true);  __syncthreads();
  {
    float winr = 0.5f * (1.f - cosf(TAU * (float)r / 24.f));
    float winc = 0.5f * (1.f - cosf(TAU * (float)c / 24.f));
    float w = winr * winc * (1.f / 576.f);
    float2 v = b0[t];
    b0[t] = make_float2(v.x * w, v.y * w);
  }
  __syncthreads();
  dft24(b0, b1, t, -1.f, false); __syncthreads();
  dft24(b1, b0, t, -1.f, true);  __syncthreads();
  int p = (r + 12) % 24, q = (c + 12) % 24;
  spec[f * 576 + p * 24 + q] = b0[t];
}

// ---------------- Stage 2: build split B and X0 = I + B/3 ----------------
__global__ void buildBX(const float2* __restrict__ spec, __hip_bfloat16* __restrict__ B,
                        __hip_bfloat16* __restrict__ X0, int c0, float scale) {
  int idx = blockIdx.x * 256 + threadIdx.x;   // 0..331775 (row*576+col, row<576)
  int cl = blockIdx.y;
  int c = c0 + cl;
  int row = idx / NK, col = idx % NK;
  int i = row / 24, j = row % 24, a = col / 24, b = col % 24;
  int u = 11 - i + a, v = 11 - j + b;
  float br = 0.f, bi = 0.f;
  if (u >= 0 && u < 24 && v >= 0 && v < 24) {
    float2 s0 = spec[(c * 2 + 0) * 576 + u * 24 + v];
    float2 s1 = spec[(c * 2 + 1) * 576 + u * 24 + v];
    float kx = (float)(a - 11), ky = (float)(b - 11);
    float xr = s0.x * kx + s1.x * ky;
    float xi = s0.y * kx + s1.y * ky;
    br = xi * scale;
    bi = -xr * scale;
  }
  size_t off = (size_t)cl * SETSTR + idx;
  __hip_bfloat16 h, l;
  bsplit(br, h, l); B[off] = h; B[off + PLN] = l;
  bsplit(bi, h, l); B[off + 2 * PLN] = h; B[off + 3 * PLN] = l;
  float d = (row == col) ? 1.f : 0.f;
  bsplit(br * (1.f / 3.f) + d, h, l); X0[off] = h; X0[off + PLN] = l;
  bsplit(bi * (1.f / 3.f), h, l);     X0[off + 2 * PLN] = h; X0[off + 3 * PLN] = l;
}

// ---------------- transpose the 4 split planes ----------------
__global__ __launch_bounds__(256) void transpose4(const __hip_bfloat16* __restrict__ src,
                                                  __hip_bfloat16* __restrict__ dst) {
  __shared__ __hip_bfloat16 tile[64][65];
  int cl = blockIdx.z;
  size_t off = (size_t)cl * SETSTR;
  int rB = blockIdx.y * 64, cB = blockIdx.x * 64;
  int tx = threadIdx.x & 63, ty = threadIdx.x >> 6;
  for (int p = 0; p < 4; ++p) {
    for (int li = 0; li < 16; ++li) {
      int r = ty * 16 + li;
      tile[r][tx] = src[off + (size_t)p * PLN + (size_t)(rB + r) * NK + cB + tx];
    }
    __syncthreads();
    for (int li = 0; li < 16; ++li) {
      int r = ty * 16 + li;
      dst[off + (size_t)p * PLN + (size_t)(cB + r) * NK + rB + tx] = tile[tx][r];
    }
    __syncthreads();
  }
}

// ---------------- Stage 3: batched split-complex MFMA GEMM, 96x96 tile ----------------
// D = alpha*(A*B) + delta*I.  A row-major [m][k] split planes; B given as BT [n][k].
// wf bit0: write D (row-major); bit1: write DT (transposed).
// 96x96 tiles: 576 = 6*96 exact (no pad-row waste, no epilogue guards).
// 256-thread blocks (4 waves, 2x2, wave tile 48x48). 36 tiles/ch -> 576 blocks.
// LDS 72 KB/block (A single 24KB restaged mid-kstep + B dbuf 2x24KB)
// -> 2 blocks/CU co-resident (144 KB < 160 KB) for cross-block TLP.
__global__ __launch_bounds__(256, 2) void cgemm_mfma(
    const __hip_bfloat16* __restrict__ A, const __hip_bfloat16* __restrict__ BT,
    __hip_bfloat16* __restrict__ D, __hip_bfloat16* __restrict__ DT,
    float alpha, float delta, int wf) {
  __shared__ char lds[73728];   // A @0 (4*6144), B bufs @24576 (2 x 4*6144)
  const int t = threadIdx.x;
  const int lane = t & 63;
  const int wid = t >> 6;                      // 0..3
  const int wm = wid >> 1, wn = wid & 1;       // 2 x 2 waves, wave tile 48x48
  // block remap: XCD-local channels when full 16-channel group (576 % 8 == 0, bijective)
  int p0 = blockIdx.x;
  int cl, tile;
  if (gridDim.x == 576) {
    int idx = p0 >> 3;
    cl = (p0 & 7) + 8 * (idx / 36);
    tile = idx % 36;
  } else {
    cl = p0 / 36;
    tile = p0 % 36;
  }
  const int rowBase = (tile / 6) * 96, colBase = (tile % 6) * 96;
  const size_t chOff = (size_t)cl * SETSTR;
  const __hip_bfloat16* Ab = A + chOff;
  const __hip_bfloat16* Bb = BT + chOff;

  // staging: A 1536 chunks (6/thread), B 1536 chunks (6/thread)
  size_t gA[6], gB[6];
  int ldsA[6], ldsB[6];
#pragma unroll
  for (int i = 0; i < 6; ++i) {
    int cid = i * 256 + t;                 // 0..1535
    int pp = cid / 384, rem = cid % 384;
    int r = rem >> 2, cp = rem & 3;        // r 0..95
    int cg = cp ^ ((r >> 1) & 3);
    gA[i] = (size_t)pp * PLN + (size_t)(rowBase + r) * NK + cg * 8;
    gB[i] = (size_t)pp * PLN + (size_t)(colBase + r) * NK + cg * 8;
    ldsA[i] = cid * 16;
    ldsB[i] = cid * 16;
  }
  // fragment read offsets (plane stride 6144)
  int aoff[3], boff[3];
#pragma unroll
  for (int mi = 0; mi < 3; ++mi) {
    int ra = wm * 48 + mi * 16 + (lane & 15);
    int ch = (lane >> 4) ^ ((ra >> 1) & 3);
    aoff[mi] = (ra * 4 + ch) * 16;
  }
#pragma unroll
  for (int ni = 0; ni < 3; ++ni) {
    int cb = wn * 48 + ni * 16 + (lane & 15);
    int ch = (lane >> 4) ^ ((cb >> 1) & 3);
    boff[ni] = (cb * 4 + ch) * 16;
  }

  f32x4 accP[3][3] = {}, accN[3][3] = {}, accI[3][3] = {};

  // prologue: tile 0 (A buf + B buf 0)
#pragma unroll
  for (int i = 0; i < 6; ++i) gld16(Ab + gA[i], &lds[ldsA[i]]);
#pragma unroll
  for (int i = 0; i < 6; ++i) gld16(Bb + gB[i], &lds[24576 + ldsB[i]]);

#define STGB(I)                                                              \
  if (ks < 17) {                                                             \
    gld16(Bb + gB[3 * (I)] + k1, &lds[24576 + (cur ^ 1) * 24576 + ldsB[3 * (I)]]);         \
    gld16(Bb + gB[3 * (I) + 1] + k1, &lds[24576 + (cur ^ 1) * 24576 + ldsB[3 * (I) + 1]]); \
    gld16(Bb + gB[3 * (I) + 2] + k1, &lds[24576 + (cur ^ 1) * 24576 + ldsB[3 * (I) + 2]]); \
  }

#define MFS(P, NI)                                                  \
  accP[P][NI] = MFMA16(arh, brh[NI], accP[P][NI]);                  \
  accP[P][NI] = MFMA16(arh, brl[NI], accP[P][NI]);                  \
  accP[P][NI] = MFMA16(arl, brh[NI], accP[P][NI]);                  \
  accN[P][NI] = MFMA16(aih, bih[NI], accN[P][NI]);                  \
  accN[P][NI] = MFMA16(aih, bil[NI], accN[P][NI]);                  \
  accN[P][NI] = MFMA16(ail, bih[NI], accN[P][NI]);                  \
  accI[P][NI] = MFMA16(arh, bih[NI], accI[P][NI]);                  \
  accI[P][NI] = MFMA16(arh, bil[NI], accI[P][NI]);                  \
  accI[P][NI] = MFMA16(arl, bih[NI], accI[P][NI]);                  \
  accI[P][NI] = MFMA16(aih, brh[NI], accI[P][NI]);                  \
  accI[P][NI] = MFMA16(aih, brl[NI], accI[P][NI]);                  \
  accI[P][NI] = MFMA16(ail, brh[NI], accI[P][NI]);

#define PHASE(P) {                                                  \
    short8 arh, arl, aih, ail;                                      \
    {                                                               \
      const char* b_ = &lds[aoff[P]];                               \
      arh = *(const short8*)(b_);                                   \
      arl = *(const short8*)(b_ + 6144);                            \
      aih = *(const short8*)(b_ + 12288);                           \
      ail = *(const short8*)(b_ + 18432);                           \
    }                                                               \
    STGB(P)                                                         \
    __builtin_amdgcn_s_setprio(1);                                  \
    MFS(P, 0) MFS(P, 1) MFS(P, 2)                                   \
    __builtin_amdgcn_s_setprio(0);                                  \
  }

#pragma unroll 1
  for (int ks = 0; ks < 18; ++ks) {
    const int cur = ks & 1;
    const int k1 = (ks + 1) * 32;
    asm volatile("s_waitcnt vmcnt(0)" ::: "memory");   // A restage + B staging landed
    __builtin_amdgcn_sched_barrier(0);
    __builtin_amdgcn_s_barrier();
    __builtin_amdgcn_sched_barrier(0);

    short8 brh[3], brl[3], bih[3], bil[3];
    {
      const char* bb = &lds[24576 + cur * 24576];
#pragma unroll
      for (int ni = 0; ni < 3; ++ni) {
        const char* base = bb + boff[ni];
        brh[ni] = *(const short8*)(base);
        brl[ni] = *(const short8*)(base + 6144);
        bih[ni] = *(const short8*)(base + 12288);
        bil[ni] = *(const short8*)(base + 18432);
      }
    }
    PHASE(0) PHASE(1)
    // phase 2: read A2, then mid-barrier (all reads of A-buf done), then re-stage A
    {
      short8 arh, arl, aih, ail;
      {
        const char* b_ = &lds[aoff[2]];
        arh = *(const short8*)(b_);
        arl = *(const short8*)(b_ + 6144);
        aih = *(const short8*)(b_ + 12288);
        ail = *(const short8*)(b_ + 18432);
      }
      asm volatile("s_waitcnt lgkmcnt(0)" ::: "memory");
      __builtin_amdgcn_sched_barrier(0);
      __builtin_amdgcn_s_barrier();                    // all waves done reading A-buf
      __builtin_amdgcn_sched_barrier(0);
      if (ks < 17) {
#pragma unroll
        for (int i = 0; i < 6; ++i) gld16(Ab + gA[i] + k1, &lds[ldsA[i]]);
      }
      __builtin_amdgcn_s_setprio(1);
      MFS(2, 0) MFS(2, 1) MFS(2, 2)
      __builtin_amdgcn_s_setprio(0);
    }
    __builtin_amdgcn_sched_barrier(0);
  }
#undef PHASE
#undef MFS
#undef STGB

  __hip_bfloat16* Dp = D + chOff;
  __hip_bfloat16* Tp = DT + chOff;
#pragma unroll
  for (int mi = 0; mi < 3; ++mi)
#pragma unroll
    for (int ni = 0; ni < 3; ++ni) {
      int rb = rowBase + wm * 48 + mi * 16 + (lane >> 4) * 4;
      int cc = colBase + wn * 48 + ni * 16 + (lane & 15);
      short hR[4], lR[4], hI[4], lI[4];
#pragma unroll
      for (int j = 0; j < 4; ++j) {
        float vR = alpha * (accP[mi][ni][j] - accN[mi][ni][j]) + ((rb + j == cc) ? delta : 0.f);
        float vI = alpha * accI[mi][ni][j];
        __hip_bfloat16 h, l;
        bsplit(vR, h, l); hR[j] = braw(h); lR[j] = braw(l);
        bsplit(vI, h, l); hI[j] = braw(h); lI[j] = braw(l);
      }
      if (wf & 1) {
#pragma unroll
        for (int j = 0; j < 4; ++j) {
          size_t o = (size_t)(rb + j) * NK + cc;
          *(short*)&Dp[o] = hR[j];
          *(short*)&Dp[PLN + o] = lR[j];
          *(short*)&Dp[2 * PLN + o] = hI[j];
          *(short*)&Dp[3 * PLN + o] = lI[j];
        }
      }
      if (wf & 2) {
        size_t o = (size_t)cc * NK + rb;
        short4v vR4 = {hR[0], hR[1], hR[2], hR[3]};
        short4v vL4 = {lR[0], lR[1], lR[2], lR[3]};
        short4v vI4 = {hI[0], hI[1], hI[2], hI[3]};
        short4v vJ4 = {lI[0], lI[1], lI[2], lI[3]};
        *(short4v*)&Tp[o] = vR4;
        *(short4v*)&Tp[PLN + o] = vL4;
        *(short4v*)&Tp[2 * PLN + o] = vI4;
        *(short4v*)&Tp[3 * PLN + o] = vJ4;
      }
    }
}

// ---------------- Stage 4: slice + roll + separable DFTs (LDS twiddle tables) ----------------
__global__ void passA(const __hip_bfloat16* __restrict__ X, float2* __restrict__ P) {
  __shared__ float2 tw[20];
  if (threadIdx.x < 20) {
    float s, c;
    sincosf((TAU / 20.f) * (float)threadIdx.x, &s, &c);
    tw[threadIdx.x] = make_float2(c, s);
  }
  __syncthreads();
  int cl = blockIdx.y;
  int idx = blockIdx.x * 256 + threadIdx.x;
  int v = idx % 20, u = (idx / 20) % 20, q = (idx / 400) % 16, p = idx / 6400;
  int pp = (p + 7) % 16;
  int qq = (q + 7) % 16;
  int row = (pp + 5) * 24 + (qq + 5);
  int uu = (u + 9) % 20;
  int aa = uu + 3;
  const __hip_bfloat16* tb = X + (size_t)cl * SETSTR;
  float2 acc = make_float2(0.f, 0.f);
  for (int vp = 0; vp < 20; ++vp) {
    int vv = (vp + 9) % 20;
    int col = aa * 24 + (vv + 3);
    size_t o = (size_t)row * NK + col;
    float xr = __bfloat162float(tb[o]) + __bfloat162float(tb[PLN + o]);
    float xi = __bfloat162float(tb[2 * PLN + o]) + __bfloat162float(tb[3 * PLN + o]);
    float2 w = tw[(v * vp) % 20];
    acc.x += xr * w.x - xi * w.y;
    acc.y += xr * w.y + xi * w.x;
  }
  P[(size_t)cl * MAPSZ + idx] = acc;
}

__global__ void passB(const float2* __restrict__ Pin, float2* __restrict__ Pout) {
  __shared__ float2 tw[20];
  if (threadIdx.x < 20) {
    float s, c;
    sincosf((TAU / 20.f) * (float)threadIdx.x, &s, &c);
    tw[threadIdx.x] = make_float2(c, s);
  }
  __syncthreads();
  int cl = blockIdx.y;
  int idx = blockIdx.x * 256 + threadIdx.x;
  int v = idx % 20, u = (idx / 20) % 20, q = (idx / 400) % 16, p = idx / 6400;
  const float2* in = Pin + (size_t)cl * MAPSZ;
  float2 acc = make_float2(0.f, 0.f);
  for (int up = 0; up < 20; ++up) {
    float2 val = in[(p * 16 + q) * 400 + up * 20 + v];
    float2 w = tw[(u * up) % 20];
    acc.x += val.x * w.x - val.y * w.y;
    acc.y += val.x * w.y + val.y * w.x;
  }
  Pout[(size_t)cl * MAPSZ + idx] = acc;
}

__global__ void passC(const float2* __restrict__ Pin, float2* __restrict__ Pout) {
  __shared__ float2 tw[16];
  if (threadIdx.x < 16) {
    float s, c;
    sincosf(-(TAU / 16.f) * (float)threadIdx.x, &s, &c);
    tw[threadIdx.x] = make_float2(c, s);
  }
  __syncthreads();
  int cl = blockIdx.y;
  int idx = blockIdx.x * 256 + threadIdx.x;
  int v = idx % 20, u = (idx / 20) % 20, q = (idx / 400) % 16, p = idx / 6400;
  const float2* in = Pin + (size_t)cl * MAPSZ;
  float2 acc = make_float2(0.f, 0.f);
  for (int qp = 0; qp < 16; ++qp) {
    float2 val = in[(p * 16 + qp) * 400 + u * 20 + v];
    float2 w = tw[(q * qp) % 16];
    acc.x += val.x * w.x - val.y * w.y;
    acc.y += val.x * w.y + val.y * w.x;
  }
  Pout[(size_t)cl * MAPSZ + idx] = acc;
}

// passD: final DFT, write split-bf16 m directly into padded [n][KOUT] planes
__global__ void passD(const float2* __restrict__ Pin, __hip_bfloat16* __restrict__ ms, int c0) {
  __shared__ float2 tw[16];
  if (threadIdx.x < 16) {
    float s, c;
    sincosf(-(TAU / 16.f) * (float)threadIdx.x, &s, &c);
    tw[threadIdx.x] = make_float2(c, s);
  }
  __syncthreads();
  int cl = blockIdx.y;
  int c = c0 + cl;
  int idx = blockIdx.x * 256 + threadIdx.x;
  int v = idx % 20, u = (idx / 20) % 20, q = (idx / 400) % 16, p = idx / 6400;
  const float2* in = Pin + (size_t)cl * MAPSZ;
  float acc = 0.f;
  for (int pp = 0; pp < 16; ++pp) {
    float2 val = in[(pp * 16 + q) * 400 + u * 20 + v];
    float2 w = tw[(p * pp) % 16];
    acc += val.x * w.x - val.y * w.y;
  }
  acc *= (1.f / 400.f);
  int n = c * 256 + idx / 400;          // o = p*16+q
  int k = idx % 400;                    // k = u*20+v
  __hip_bfloat16 h, l;
  bsplit(acc, h, l);
  ms[(size_t)n * KOUT + k] = h;
  ms[MPL + (size_t)n * KOUT + k] = l;
}

// zero the k in [400,416) pad of the m planes
__global__ void pad_m(__hip_bfloat16* __restrict__ ms) {
  int idx = blockIdx.x * 256 + threadIdx.x;   // 4096*16*2
  int p = idx >> 16;
  int rem = idx & 65535;
  int n = rem >> 4;
  int k = 400 + (rem & 15);
  ms[(size_t)p * MPL + (size_t)n * KOUT + k] = __float2bfloat16(0.f);
}

// convert x (8192x400 f32) to bf16 padded [8192][KOUT] (hi only)
__global__ void prep_x(const float* __restrict__ x, __hip_bfloat16* __restrict__ xs) {
  int idx = blockIdx.x * 256 + threadIdx.x;   // 8192*52
  if (idx >= 8192 * 52) return;
  int b = idx / 52, c8 = idx % 52;
  int k = c8 * 8;
  short8 hh = {};
  if (k < 400) {
    const float4* xp = (const float4*)(x + (size_t)b * 400 + k);
    float4 v0 = xp[0], v1 = xp[1];
    float vals[8] = {v0.x, v0.y, v0.z, v0.w, v1.x, v1.y, v1.z, v1.w};
#pragma unroll
    for (int i = 0; i < 8; ++i) hh[i] = braw(__float2bfloat16(vals[i]));
  }
  *(short8*)(xs + (size_t)b * KOUT + k) = hh;
}

// ---------------- Stage 5: output GEMM, x bf16 x m split-bf16, 128x128 tile ----------------
__global__ __launch_bounds__(512, 2) void out_mfma(
    const __hip_bfloat16* __restrict__ xs, const __hip_bfloat16* __restrict__ ms,
    float* __restrict__ Y) {
  __shared__ char lds[2][24576];   // A @0 (8192), B planes @8192 (2*8192)
  const int t = threadIdx.x;
  const int lane = t & 63;
  const int wid = t >> 6;
  const int wm = wid >> 2, wn = wid & 3;
  const int rowBase = blockIdx.y * 128, colBase = blockIdx.x * 128;

  size_t gA1, gB[2];
  int ldsA1, ldsB[2];
  {
    int cid = t;                          // 0..511 A chunks
    int r = (cid >> 2) & 127, cp = cid & 3;
    int cg = cp ^ ((r >> 1) & 3);
    gA1 = (size_t)(rowBase + r) * KOUT + cg * 8;
    ldsA1 = cid * 16;
  }
#pragma unroll
  for (int i = 0; i < 2; ++i) {
    int cid = i * 512 + t;                // 0..1023 B chunks
    int pp = cid >> 9, r = (cid >> 2) & 127, cp = cid & 3;
    int cg = cp ^ ((r >> 1) & 3);
    gB[i] = (size_t)pp * MPL + (size_t)(colBase + r) * KOUT + cg * 8;
    ldsB[i] = 8192 + cid * 16;
  }
  int aoff[4], boff[2];
#pragma unroll
  for (int mi = 0; mi < 4; ++mi) {
    int ra = wm * 64 + mi * 16 + (lane & 15);
    int ch = (lane >> 4) ^ ((ra >> 1) & 3);
    aoff[mi] = (ra * 4 + ch) * 16;
  }
#pragma unroll
  for (int ni = 0; ni < 2; ++ni) {
    int cb = wn * 32 + ni * 16 + (lane & 15);
    int ch = (lane >> 4) ^ ((cb >> 1) & 3);
    boff[ni] = 8192 + (cb * 4 + ch) * 16;
  }

  f32x4 acc[4][2] = {};

  // prologue
  gld16(xs + gA1, &lds[0][ldsA1]);
  gld16(ms + gB[0], &lds[0][ldsB[0]]);
  gld16(ms + gB[1], &lds[0][ldsB[1]]);

#pragma unroll 1
  for (int ks = 0; ks < 13; ++ks) {
    int cur = ks & 1;
    int k1 = (ks + 1) * 32;
    asm volatile("s_waitcnt vmcnt(0)" ::: "memory");
    __builtin_amdgcn_sched_barrier(0);
    __builtin_amdgcn_s_barrier();
    __builtin_amdgcn_sched_barrier(0);
    short8 bh[2], bl[2];
#pragma unroll
    for (int ni = 0; ni < 2; ++ni) {
      const char* base = &lds[cur][boff[ni]];
      bh[ni] = *(const short8*)(base);
      bl[ni] = *(const short8*)(base + 8192);
    }
#pragma unroll
    for (int mi = 0; mi < 4; ++mi) {
      short8 ah;
      {
        const char* base = &lds[cur][aoff[mi]];
        ah = *(const short8*)(base);
      }
      if (ks < 12) {
        if (mi == 0) gld16(xs + gA1 + k1, &lds[cur ^ 1][ldsA1]);
        else if (mi == 1) gld16(ms + gB[0] + k1, &lds[cur ^ 1][ldsB[0]]);
        else if (mi == 2) gld16(ms + gB[1] + k1, &lds[cur ^ 1][ldsB[1]]);
      }
      __builtin_amdgcn_s_setprio(1);
#pragma unroll
      for (int ni = 0; ni < 2; ++ni) {
        acc[mi][ni] = MFMA16(ah, bh[ni], acc[mi][ni]);
        acc[mi][ni] = MFMA16(ah, bl[ni], acc[mi][ni]);
      }
      __builtin_amdgcn_s_setprio(0);
    }
    __builtin_amdgcn_sched_barrier(0);
  }

#pragma unroll
  for (int mi = 0; mi < 4; ++mi)
#pragma unroll
    for (int ni = 0; ni < 2; ++ni) {
      int rb = rowBase + wm * 64 + mi * 16 + (lane >> 4) * 4;
      int cc = colBase + wn * 32 + ni * 16 + (lane & 15);
#pragma unroll
      for (int j = 0; j < 4; ++j)
        Y[(size_t)(rb + j) * 4096 + cc] = acc[mi][ni][j];
    }
}

// ---------------- Launcher ----------------
extern "C" void kernel_launch(void* const* d_in, const int* in_sizes, int n_in,
                              void* d_out, int out_size, void* d_ws, size_t ws_size,
                              hipStream_t stream) {
  const float* x = (const float*)d_in[0];     // (8192,1,20,20)
  const float* sig = (const float*)d_in[1];   // (16,2,24,24)
  float* out = (float*)d_out;                 // (8192,16,16,16)
  char* ws = (char*)d_ws;

  const size_t specBytes = 32ull * 576 * sizeof(float2);
  const size_t xsBytes = XPL * 2;                       // one bf16 plane
  const size_t msBytes = 2ull * MPL * 2;
  const size_t fixed = specBytes + xsBytes + msBytes;
  const size_t setB = SETSTR * 2;                       // bytes per split set
  const size_t perCh = 5 * setB + 2ull * MAPSZ * 8;     // B, X0, X0T, X1, X1T + P0/P1

  int cg = 1;
  if (ws_size > fixed) {
    size_t av = (ws_size - fixed) / perCh;
    cg = (av < 1) ? 1 : (av > 16 ? 16 : (int)av);
  }

  float2* spec = (float2*)ws;
  __hip_bfloat16* xs = (__hip_bfloat16*)(ws + specBytes);
  __hip_bfloat16* ms = (__hip_bfloat16*)(ws + specBytes + xsBytes);
  __hip_bfloat16* Bst = (__hip_bfloat16*)(ws + fixed);
  __hip_bfloat16* X0 = Bst + (size_t)cg * SETSTR;
  __hip_bfloat16* X0T = X0 + (size_t)cg * SETSTR;
  __hip_bfloat16* X1 = X0T + (size_t)cg * SETSTR;
  __hip_bfloat16* X1T = X1 + (size_t)cg * SETSTR;
  float2* P0 = (float2*)(X1T + (size_t)cg * SETSTR);
  float2* P1 = P0 + (size_t)cg * MAPSZ;

  spectrum_kernel<<<dim3(32), dim3(576), 0, stream>>>(sig, spec);
  prep_x<<<dim3((8192 * 52 + 255) / 256), dim3(256), 0, stream>>>(x, xs);
  pad_m<<<dim3(512), dim3(256), 0, stream>>>(ms);

  const float scale = 1.f / 64.f;  // s = 6 squarings
  for (int c0 = 0; c0 < 16; c0 += cg) {
    int g = (16 - c0 < cg) ? (16 - c0) : cg;
    buildBX<<<dim3(1296, g), dim3(256), 0, stream>>>(spec, Bst, X0, c0, scale);
    transpose4<<<dim3(9, 9, g), dim3(256), 0, stream>>>(X0, X0T);
    __hip_bfloat16 *xr = X0, *xt = X0T, *yr = X1, *yt = X1T;
    // Horner (Taylor order 3): X <- I + (B*X)/k, k=2..1. Only DT consumed until k=1.
    for (int k = 2; k >= 1; --k) {
      int wf = (k == 1) ? 3 : 2;
      cgemm_mfma<<<dim3(36 * g), dim3(256), 0, stream>>>(Bst, xt, yr, yt,
                                                         1.f / (float)k, 1.f, wf);
      __hip_bfloat16* tmp;
      tmp = xr; xr = yr; yr = tmp;
      tmp = xt; xt = yt; yt = tmp;
    }
    // 6 squarings; last one only needs row-major output (feeds passA)
    for (int t8 = 0; t8 < 6; ++t8) {
      int wf = (t8 == 5) ? 1 : 3;
      cgemm_mfma<<<dim3(36 * g), dim3(256), 0, stream>>>(xr, xt, yr, yt, 1.f, 0.f, wf);
      __hip_bfloat16* tmp;
      tmp = xr; xr = yr; yr = tmp;
      tmp = xt; xt = yt; yt = tmp;
    }
    passA<<<dim3(400, g), dim3(256), 0, stream>>>(xr, P0);
    passB<<<dim3(400, g), dim3(256), 0, stream>>>(P0, P1);
    passC<<<dim3(400, g), dim3(256), 0, stream>>>(P1, P0);
    passD<<<dim3(400, g), dim3(256), 0, stream>>>(P0, ms, c0);
  }

  out_mfma<<<dim3(32, 64), dim3(512), 0, stream>>>(xs, ms, out);
}

// Round 14
// 666.109 us; speedup vs baseline: 1.3759x; 1.3759x over previous
//
#include <hip/hip_runtime.h>
#include <hip/hip_bf16.h>
#include <math.h>

#define TAU 6.283185307179586f
#define NK 576                    // matrix dimension (K always exact: 18*32)
#define NPAD 640                  // padded row count for 128-row tiles
#define PLN ((size_t)NPAD * NK)   // elems per padded plane = 368640
#define SETSTR ((size_t)4 * PLN)  // elems per 4-plane split set
#define MAPSZ 102400              // 16*16*20*20
#define KOUT 416                  // padded K for output gemm (13*32)
#define XPL ((size_t)8192 * KOUT)
#define MPL ((size_t)4096 * KOUT)

typedef __attribute__((ext_vector_type(8))) short short8;
typedef __attribute__((ext_vector_type(4))) short short4v;
typedef __attribute__((ext_vector_type(4))) float f32x4;

__device__ inline void bsplit(float v, __hip_bfloat16& h, __hip_bfloat16& l) {
  h = __float2bfloat16(v);
  l = __float2bfloat16(v - __bfloat162float(h));
}
__device__ inline short braw(__hip_bfloat16 b) { return *reinterpret_cast<short*>(&b); }

__device__ inline void gld16(const void* g, const void* l) {
  __builtin_amdgcn_global_load_lds((const __attribute__((address_space(1))) unsigned*)g,
                                   (__attribute__((address_space(3))) unsigned*)l, 16, 0, 0);
}

#define MFMA16(a, b, c) __builtin_amdgcn_mfma_f32_16x16x32_bf16(a, b, c, 0, 0, 0)

// ---------------- Stage 1: signal -> spectrum ----------------
__device__ inline void dft24(const float2* in, float2* out, int t, float sgn, bool firstAxis) {
  int r = t / 24, c = t % 24;
  int kk = firstAxis ? r : c;
  float2 acc = make_float2(0.f, 0.f);
  for (int n = 0; n < 24; ++n) {
    float ang = sgn * (TAU / 24.f) * (float)((kk * n) % 24);
    float s, co;
    sincosf(ang, &s, &co);
    float2 v = firstAxis ? in[n * 24 + c] : in[r * 24 + n];
    acc.x += v.x * co - v.y * s;
    acc.y += v.x * s + v.y * co;
  }
  out[t] = acc;
}

__global__ void spectrum_kernel(const float* __restrict__ sig, float2* __restrict__ spec) {
  __shared__ float2 b0[576];
  __shared__ float2 b1[576];
  int f = blockIdx.x;
  int t = threadIdx.x;
  int r = t / 24, c = t % 24;
  b0[t] = make_float2(sig[f * 576 + t], 0.f);
  __syncthreads();
  dft24(b0, b1, t, -1.f, false); __syncthreads();
  dft24(b1, b0, t, -1.f, true);  __syncthreads();
  {
    int p2 = (r + 12) % 24 - 11;
    int q2 = (c + 12) % 24 - 11;
    float rr = (float)(1 + p2 * p2 + q2 * q2) * 5.f;
    float2 v = b0[t];
    b0[t] = make_float2(v.x / rr, v.y / rr);
  }
  __syncthreads();
  dft24(b0, b1, t, +1.f, false); __syncthreads();
  dft24(b1, b0, t, +1.f, true);  __syncthreads();
  {
    float winr = 0.5f * (1.f - cosf(TAU * (float)r / 24.f));
    float winc = 0.5f * (1.f - cosf(TAU * (float)c / 24.f));
    float w = winr * winc * (1.f / 576.f);
    float2 v = b0[t];
    b0[t] = make_float2(v.x * w, v.y * w);
  }
  __syncthreads();
  dft24(b0, b1, t, -1.f, false); __syncthreads();
  dft24(b1, b0, t, -1.f, true);  __syncthreads();
  int p = (r + 12) % 24, q = (c + 12) % 24;
  spec[f * 576 + p * 24 + q] = b0[t];
}

// ---------------- Stage 2: build split B and X0 = I + B/3 ----------------
__global__ void buildBX(const float2* __restrict__ spec, __hip_bfloat16* __restrict__ B,
                        __hip_bfloat16* __restrict__ X0, int c0, float scale) {
  int idx = blockIdx.x * 256 + threadIdx.x;   // 0..331775 (row*576+col, row<576)
  int cl = blockIdx.y;
  int c = c0 + cl;
  int row = idx / NK, col = idx % NK;
  int i = row / 24, j = row % 24, a = col / 24, b = col % 24;
  int u = 11 - i + a, v = 11 - j + b;
  float br = 0.f, bi = 0.f;
  if (u >= 0 && u < 24 && v >= 0 && v < 24) {
    float2 s0 = spec[(c * 2 + 0) * 576 + u * 24 + v];
    float2 s1 = spec[(c * 2 + 1) * 576 + u * 24 + v];
    float kx = (float)(a - 11), ky = (float)(b - 11);
    float xr = s0.x * kx + s1.x * ky;
    float xi = s0.y * kx + s1.y * ky;
    br = xi * scale;
    bi = -xr * scale;
  }
  size_t off = (size_t)cl * SETSTR + idx;
  __hip_bfloat16 h, l;
  bsplit(br, h, l); B[off] = h; B[off + PLN] = l;
  bsplit(bi, h, l); B[off + 2 * PLN] = h; B[off + 3 * PLN] = l;
  float d = (row == col) ? 1.f : 0.f;
  bsplit(br * (1.f / 3.f) + d, h, l); X0[off] = h; X0[off + PLN] = l;
  bsplit(bi * (1.f / 3.f), h, l);     X0[off + 2 * PLN] = h; X0[off + 3 * PLN] = l;
}

// ---------------- transpose the 4 split planes ----------------
__global__ __launch_bounds__(256) void transpose4(const __hip_bfloat16* __restrict__ src,
                                                  __hip_bfloat16* __restrict__ dst) {
  __shared__ __hip_bfloat16 tile[64][65];
  int cl = blockIdx.z;
  size_t off = (size_t)cl * SETSTR;
  int rB = blockIdx.y * 64, cB = blockIdx.x * 64;
  int tx = threadIdx.x & 63, ty = threadIdx.x >> 6;
  for (int p = 0; p < 4; ++p) {
    for (int li = 0; li < 16; ++li) {
      int r = ty * 16 + li;
      tile[r][tx] = src[off + (size_t)p * PLN + (size_t)(rB + r) * NK + cB + tx];
    }
    __syncthreads();
    for (int li = 0; li < 16; ++li) {
      int r = ty * 16 + li;
      dst[off + (size_t)p * PLN + (size_t)(cB + r) * NK + rB + tx] = tile[tx][r];
    }
    __syncthreads();
  }
}

// ---------------- Stage 3: batched split-complex MFMA GEMM, 128x192 tile ----------------
// (round-10 best-measured config: 88 us/dispatch ~ 834 TF, the 2-barrier-structure ceiling)
__global__ __launch_bounds__(512, 2) void cgemm_mfma(
    const __hip_bfloat16* __restrict__ A, const __hip_bfloat16* __restrict__ BT,
    __hip_bfloat16* __restrict__ D, __hip_bfloat16* __restrict__ DT,
    float alpha, float delta, int wf) {
  __shared__ char lds[2][81920];   // per buf: A planes @0 (4*8192), B planes @32768 (4*12288)
  const int t = threadIdx.x;
  const int lane = t & 63;
  const int wid = t >> 6;
  const int wm = wid >> 2, wn = wid & 3;          // 2 x 4 waves, wave tile 64x48
  int p0 = blockIdx.x;
  int cl, tile;
  if (gridDim.x == 240) {
    int idx = p0 >> 3;
    cl = (p0 & 7) + 8 * (idx / 15);
    tile = idx % 15;
  } else {
    cl = p0 / 15;
    tile = p0 % 15;
  }
  const int rowBase = (tile / 3) * 128, colBase = (tile % 3) * 192;
  const size_t chOff = (size_t)cl * SETSTR;
  const __hip_bfloat16* Ab = A + chOff;
  const __hip_bfloat16* Bb = BT + chOff;

  size_t gA[4], gB[6];
  int ldsA[4], ldsB[6];
#pragma unroll
  for (int i = 0; i < 4; ++i) {
    int cid = i * 512 + t;                 // 0..2047
    int pp = cid >> 9, r = (cid >> 2) & 127, cp = cid & 3;
    int cg = cp ^ ((r >> 1) & 3);
    gA[i] = (size_t)pp * PLN + (size_t)(rowBase + r) * NK + cg * 8;
    ldsA[i] = cid * 16;
  }
#pragma unroll
  for (int i = 0; i < 6; ++i) {
    int cid = i * 512 + t;                 // 0..3071
    int pp = cid / 768, rem = cid % 768;
    int r = rem >> 2, cp = rem & 3;
    int cg = cp ^ ((r >> 1) & 3);
    gB[i] = (size_t)pp * PLN + (size_t)(colBase + r) * NK + cg * 8;
    ldsB[i] = 32768 + cid * 16;
  }
  int aoff[4], boff[3];
#pragma unroll
  for (int mi = 0; mi < 4; ++mi) {
    int ra = wm * 64 + mi * 16 + (lane & 15);
    int ch = (lane >> 4) ^ ((ra >> 1) & 3);
    aoff[mi] = (ra * 4 + ch) * 16;
  }
#pragma unroll
  for (int ni = 0; ni < 3; ++ni) {
    int cb = wn * 48 + ni * 16 + (lane & 15);
    int ch = (lane >> 4) ^ ((cb >> 1) & 3);
    boff[ni] = 32768 + (cb * 4 + ch) * 16;
  }

  f32x4 accP[4][3] = {}, accN[4][3] = {}, accI[4][3] = {};

#pragma unroll
  for (int i = 0; i < 4; ++i) gld16(Ab + gA[i], &lds[0][ldsA[i]]);
#pragma unroll
  for (int i = 0; i < 6; ++i) gld16(Bb + gB[i], &lds[0][ldsB[i]]);

#pragma unroll 1
  for (int ks = 0; ks < 18; ++ks) {
    const int cur = ks & 1;
    const int k1 = (ks + 1) * 32;
    asm volatile("s_waitcnt vmcnt(0)" ::: "memory");
    __builtin_amdgcn_sched_barrier(0);
    __builtin_amdgcn_s_barrier();
    __builtin_amdgcn_sched_barrier(0);

    short8 brh[3], brl[3], bih[3], bil[3];
#pragma unroll
    for (int ni = 0; ni < 3; ++ni) {
      const char* base = &lds[cur][boff[ni]];
      brh[ni] = *(const short8*)(base);
      brl[ni] = *(const short8*)(base + 12288);
      bih[ni] = *(const short8*)(base + 24576);
      bil[ni] = *(const short8*)(base + 36864);
    }
#pragma unroll
    for (int p = 0; p < 4; ++p) {
      short8 arh, arl, aih, ail;
      {
        const char* base = &lds[cur][aoff[p]];
        arh = *(const short8*)(base);
        arl = *(const short8*)(base + 8192);
        aih = *(const short8*)(base + 16384);
        ail = *(const short8*)(base + 24576);
      }
      if (ks < 17) {
        if (p == 0) {
          gld16(Ab + gA[0] + k1, &lds[cur ^ 1][ldsA[0]]);
          gld16(Ab + gA[1] + k1, &lds[cur ^ 1][ldsA[1]]);
          gld16(Ab + gA[2] + k1, &lds[cur ^ 1][ldsA[2]]);
          gld16(Ab + gA[3] + k1, &lds[cur ^ 1][ldsA[3]]);
        } else if (p == 1) {
          gld16(Bb + gB[0] + k1, &lds[cur ^ 1][ldsB[0]]);
          gld16(Bb + gB[1] + k1, &lds[cur ^ 1][ldsB[1]]);
          gld16(Bb + gB[2] + k1, &lds[cur ^ 1][ldsB[2]]);
        } else if (p == 2) {
          gld16(Bb + gB[3] + k1, &lds[cur ^ 1][ldsB[3]]);
          gld16(Bb + gB[4] + k1, &lds[cur ^ 1][ldsB[4]]);
          gld16(Bb + gB[5] + k1, &lds[cur ^ 1][ldsB[5]]);
        }
      }
      __builtin_amdgcn_s_setprio(1);
#pragma unroll
      for (int ni = 0; ni < 3; ++ni) {
        accP[p][ni] = MFMA16(arh, brh[ni], accP[p][ni]);
        accP[p][ni] = MFMA16(arh, brl[ni], accP[p][ni]);
        accP[p][ni] = MFMA16(arl, brh[ni], accP[p][ni]);
        accN[p][ni] = MFMA16(aih, bih[ni], accN[p][ni]);
        accN[p][ni] = MFMA16(aih, bil[ni], accN[p][ni]);
        accN[p][ni] = MFMA16(ail, bih[ni], accN[p][ni]);
        accI[p][ni] = MFMA16(arh, bih[ni], accI[p][ni]);
        accI[p][ni] = MFMA16(arh, bil[ni], accI[p][ni]);
        accI[p][ni] = MFMA16(arl, bih[ni], accI[p][ni]);
        accI[p][ni] = MFMA16(aih, brh[ni], accI[p][ni]);
        accI[p][ni] = MFMA16(aih, brl[ni], accI[p][ni]);
        accI[p][ni] = MFMA16(ail, brh[ni], accI[p][ni]);
      }
      __builtin_amdgcn_s_setprio(0);
    }
    __builtin_amdgcn_sched_barrier(0);
  }

  __hip_bfloat16* Dp = D + chOff;
  __hip_bfloat16* Tp = DT + chOff;
#pragma unroll
  for (int mi = 0; mi < 4; ++mi)
#pragma unroll
    for (int ni = 0; ni < 3; ++ni) {
      int rb = rowBase + wm * 64 + mi * 16 + (lane >> 4) * 4;
      int cc = colBase + wn * 48 + ni * 16 + (lane & 15);
      if (rb >= NK) continue;
      short hR[4], lR[4], hI[4], lI[4];
#pragma unroll
      for (int j = 0; j < 4; ++j) {
        float vR = alpha * (accP[mi][ni][j] - accN[mi][ni][j]) + ((rb + j == cc) ? delta : 0.f);
        float vI = alpha * accI[mi][ni][j];
        __hip_bfloat16 h, l;
        bsplit(vR, h, l); hR[j] = braw(h); lR[j] = braw(l);
        bsplit(vI, h, l); hI[j] = braw(h); lI[j] = braw(l);
      }
      if (wf & 1) {
#pragma unroll
        for (int j = 0; j < 4; ++j) {
          size_t o = (size_t)(rb + j) * NK + cc;
          *(short*)&Dp[o] = hR[j];
          *(short*)&Dp[PLN + o] = lR[j];
          *(short*)&Dp[2 * PLN + o] = hI[j];
          *(short*)&Dp[3 * PLN + o] = lI[j];
        }
      }
      if (wf & 2) {
        size_t o = (size_t)cc * NK + rb;
        short4v vR4 = {hR[0], hR[1], hR[2], hR[3]};
        short4v vL4 = {lR[0], lR[1], lR[2], lR[3]};
        short4v vI4 = {hI[0], hI[1], hI[2], hI[3]};
        short4v vJ4 = {lI[0], lI[1], lI[2], lI[3]};
        *(short4v*)&Tp[o] = vR4;
        *(short4v*)&Tp[PLN + o] = vL4;
        *(short4v*)&Tp[2 * PLN + o] = vI4;
        *(short4v*)&Tp[3 * PLN + o] = vJ4;
      }
    }
}

// ---------------- Stage 4: slice + roll + separable DFTs (LDS twiddle tables) ----------------
__global__ void passA(const __hip_bfloat16* __restrict__ X, float2* __restrict__ P) {
  __shared__ float2 tw[20];
  if (threadIdx.x < 20) {
    float s, c;
    sincosf((TAU / 20.f) * (float)threadIdx.x, &s, &c);
    tw[threadIdx.x] = make_float2(c, s);
  }
  __syncthreads();
  int cl = blockIdx.y;
  int idx = blockIdx.x * 256 + threadIdx.x;
  int v = idx % 20, u = (idx / 20) % 20, q = (idx / 400) % 16, p = idx / 6400;
  int pp = (p + 7) % 16;
  int qq = (q + 7) % 16;
  int row = (pp + 5) * 24 + (qq + 5);
  int uu = (u + 9) % 20;
  int aa = uu + 3;
  const __hip_bfloat16* tb = X + (size_t)cl * SETSTR;
  float2 acc = make_float2(0.f, 0.f);
  for (int vp = 0; vp < 20; ++vp) {
    int vv = (vp + 9) % 20;
    int col = aa * 24 + (vv + 3);
    size_t o = (size_t)row * NK + col;
    float xr = __bfloat162float(tb[o]) + __bfloat162float(tb[PLN + o]);
    float xi = __bfloat162float(tb[2 * PLN + o]) + __bfloat162float(tb[3 * PLN + o]);
    float2 w = tw[(v * vp) % 20];
    acc.x += xr * w.x - xi * w.y;
    acc.y += xr * w.y + xi * w.x;
  }
  P[(size_t)cl * MAPSZ + idx] = acc;
}

__global__ void passB(const float2* __restrict__ Pin, float2* __restrict__ Pout) {
  __shared__ float2 tw[20];
  if (threadIdx.x < 20) {
    float s, c;
    sincosf((TAU / 20.f) * (float)threadIdx.x, &s, &c);
    tw[threadIdx.x] = make_float2(c, s);
  }
  __syncthreads();
  int cl = blockIdx.y;
  int idx = blockIdx.x * 256 + threadIdx.x;
  int v = idx % 20, u = (idx / 20) % 20, q = (idx / 400) % 16, p = idx / 6400;
  const float2* in = Pin + (size_t)cl * MAPSZ;
  float2 acc = make_float2(0.f, 0.f);
  for (int up = 0; up < 20; ++up) {
    float2 val = in[(p * 16 + q) * 400 + up * 20 + v];
    float2 w = tw[(u * up) % 20];
    acc.x += val.x * w.x - val.y * w.y;
    acc.y += val.x * w.y + val.y * w.x;
  }
  Pout[(size_t)cl * MAPSZ + idx] = acc;
}

__global__ void passC(const float2* __restrict__ Pin, float2* __restrict__ Pout) {
  __shared__ float2 tw[16];
  if (threadIdx.x < 16) {
    float s, c;
    sincosf(-(TAU / 16.f) * (float)threadIdx.x, &s, &c);
    tw[threadIdx.x] = make_float2(c, s);
  }
  __syncthreads();
  int cl = blockIdx.y;
  int idx = blockIdx.x * 256 + threadIdx.x;
  int v = idx % 20, u = (idx / 20) % 20, q = (idx / 400) % 16, p = idx / 6400;
  const float2* in = Pin + (size_t)cl * MAPSZ;
  float2 acc = make_float2(0.f, 0.f);
  for (int qp = 0; qp < 16; ++qp) {
    float2 val = in[(p * 16 + qp) * 400 + u * 20 + v];
    float2 w = tw[(q * qp) % 16];
    acc.x += val.x * w.x - val.y * w.y;
    acc.y += val.x * w.y + val.y * w.x;
  }
  Pout[(size_t)cl * MAPSZ + idx] = acc;
}

// passD: final DFT, write bf16 m (hi only) into padded [n][KOUT] plane
__global__ void passD(const float2* __restrict__ Pin, __hip_bfloat16* __restrict__ ms, int c0) {
  __shared__ float2 tw[16];
  if (threadIdx.x < 16) {
    float s, c;
    sincosf(-(TAU / 16.f) * (float)threadIdx.x, &s, &c);
    tw[threadIdx.x] = make_float2(c, s);
  }
  __syncthreads();
  int cl = blockIdx.y;
  int c = c0 + cl;
  int idx = blockIdx.x * 256 + threadIdx.x;
  int v = idx % 20, u = (idx / 20) % 20, q = (idx / 400) % 16, p = idx / 6400;
  const float2* in = Pin + (size_t)cl * MAPSZ;
  float acc = 0.f;
  for (int pp = 0; pp < 16; ++pp) {
    float2 val = in[(pp * 16 + q) * 400 + u * 20 + v];
    float2 w = tw[(p * pp) % 16];
    acc += val.x * w.x - val.y * w.y;
  }
  acc *= (1.f / 400.f);
  int n = c * 256 + idx / 400;          // o = p*16+q
  int k = idx % 400;                    // k = u*20+v
  ms[(size_t)n * KOUT + k] = __float2bfloat16(acc);
}

// zero the k in [400,416) pad of the m plane (hi only)
__global__ void pad_m(__hip_bfloat16* __restrict__ ms) {
  int idx = blockIdx.x * 256 + threadIdx.x;   // 4096*16
  int n = idx >> 4;
  int k = 400 + (idx & 15);
  ms[(size_t)n * KOUT + k] = __float2bfloat16(0.f);
}

// convert x (8192x400 f32) to bf16 padded [8192][KOUT] (hi only)
__global__ void prep_x(const float* __restrict__ x, __hip_bfloat16* __restrict__ xs) {
  int idx = blockIdx.x * 256 + threadIdx.x;   // 8192*52
  if (idx >= 8192 * 52) return;
  int b = idx / 52, c8 = idx % 52;
  int k = c8 * 8;
  short8 hh = {};
  if (k < 400) {
    const float4* xp = (const float4*)(x + (size_t)b * 400 + k);
    float4 v0 = xp[0], v1 = xp[1];
    float vals[8] = {v0.x, v0.y, v0.z, v0.w, v1.x, v1.y, v1.z, v1.w};
#pragma unroll
    for (int i = 0; i < 8; ++i) hh[i] = braw(__float2bfloat16(vals[i]));
  }
  *(short8*)(xs + (size_t)b * KOUT + k) = hh;
}

// ---------------- Stage 5: output GEMM, x bf16 x m bf16, 128x128 tile ----------------
// LDS per buf: A 8KB + B 8KB = 16KB; 32KB total -> 4+ blocks/CU.
__global__ __launch_bounds__(512, 2) void out_mfma(
    const __hip_bfloat16* __restrict__ xs, const __hip_bfloat16* __restrict__ ms,
    float* __restrict__ Y) {
  __shared__ char lds[2][16384];   // A @0 (8192), B @8192
  const int t = threadIdx.x;
  const int lane = t & 63;
  const int wid = t >> 6;
  const int wm = wid >> 2, wn = wid & 3;
  const int rowBase = blockIdx.y * 128, colBase = blockIdx.x * 128;

  size_t gA1, gB1;
  int ldsA1, ldsB1;
  {
    int cid = t;                          // 0..511
    int r = (cid >> 2) & 127, cp = cid & 3;
    int cg = cp ^ ((r >> 1) & 3);
    gA1 = (size_t)(rowBase + r) * KOUT + cg * 8;
    gB1 = (size_t)(colBase + r) * KOUT + cg * 8;
    ldsA1 = cid * 16;
    ldsB1 = 8192 + cid * 16;
  }
  int aoff[4], boff[2];
#pragma unroll
  for (int mi = 0; mi < 4; ++mi) {
    int ra = wm * 64 + mi * 16 + (lane & 15);
    int ch = (lane >> 4) ^ ((ra >> 1) & 3);
    aoff[mi] = (ra * 4 + ch) * 16;
  }
#pragma unroll
  for (int ni = 0; ni < 2; ++ni) {
    int cb = wn * 32 + ni * 16 + (lane & 15);
    int ch = (lane >> 4) ^ ((cb >> 1) & 3);
    boff[ni] = 8192 + (cb * 4 + ch) * 16;
  }

  f32x4 acc[4][2] = {};

  gld16(xs + gA1, &lds[0][ldsA1]);
  gld16(ms + gB1, &lds[0][ldsB1]);

#pragma unroll 1
  for (int ks = 0; ks < 13; ++ks) {
    int cur = ks & 1;
    int k1 = (ks + 1) * 32;
    asm volatile("s_waitcnt vmcnt(0)" ::: "memory");
    __builtin_amdgcn_sched_barrier(0);
    __builtin_amdgcn_s_barrier();
    __builtin_amdgcn_sched_barrier(0);
    short8 bh[2];
#pragma unroll
    for (int ni = 0; ni < 2; ++ni)
      bh[ni] = *(const short8*)(&lds[cur][boff[ni]]);
#pragma unroll
    for (int mi = 0; mi < 4; ++mi) {
      short8 ah = *(const short8*)(&lds[cur][aoff[mi]]);
      if (ks < 12) {
        if (mi == 0) gld16(xs + gA1 + k1, &lds[cur ^ 1][ldsA1]);
        else if (mi == 1) gld16(ms + gB1 + k1, &lds[cur ^ 1][ldsB1]);
      }
      __builtin_amdgcn_s_setprio(1);
#pragma unroll
      for (int ni = 0; ni < 2; ++ni)
        acc[mi][ni] = MFMA16(ah, bh[ni], acc[mi][ni]);
      __builtin_amdgcn_s_setprio(0);
    }
    __builtin_amdgcn_sched_barrier(0);
  }

#pragma unroll
  for (int mi = 0; mi < 4; ++mi)
#pragma unroll
    for (int ni = 0; ni < 2; ++ni) {
      int rb = rowBase + wm * 64 + mi * 16 + (lane >> 4) * 4;
      int cc = colBase + wn * 32 + ni * 16 + (lane & 15);
#pragma unroll
      for (int j = 0; j < 4; ++j)
        Y[(size_t)(rb + j) * 4096 + cc] = acc[mi][ni][j];
    }
}

// ---------------- Launcher ----------------
extern "C" void kernel_launch(void* const* d_in, const int* in_sizes, int n_in,
                              void* d_out, int out_size, void* d_ws, size_t ws_size,
                              hipStream_t stream) {
  const float* x = (const float*)d_in[0];     // (8192,1,20,20)
  const float* sig = (const float*)d_in[1];   // (16,2,24,24)
  float* out = (float*)d_out;                 // (8192,16,16,16)
  char* ws = (char*)d_ws;

  const size_t specBytes = 32ull * 576 * sizeof(float2);
  const size_t xsBytes = XPL * 2;                       // one bf16 plane
  const size_t msBytes = MPL * 2;                       // one bf16 plane
  const size_t fixed = specBytes + xsBytes + msBytes;
  const size_t setB = SETSTR * 2;                       // bytes per split set
  const size_t perCh = 5 * setB + 2ull * MAPSZ * 8;     // B, X0, X0T, X1, X1T + P0/P1

  int cg = 1;
  if (ws_size > fixed) {
    size_t av = (ws_size - fixed) / perCh;
    cg = (av < 1) ? 1 : (av > 16 ? 16 : (int)av);
  }

  float2* spec = (float2*)ws;
  __hip_bfloat16* xs = (__hip_bfloat16*)(ws + specBytes);
  __hip_bfloat16* ms = (__hip_bfloat16*)(ws + specBytes + xsBytes);
  __hip_bfloat16* Bst = (__hip_bfloat16*)(ws + fixed);
  __hip_bfloat16* X0 = Bst + (size_t)cg * SETSTR;
  __hip_bfloat16* X0T = X0 + (size_t)cg * SETSTR;
  __hip_bfloat16* X1 = X0T + (size_t)cg * SETSTR;
  __hip_bfloat16* X1T = X1 + (size_t)cg * SETSTR;
  float2* P0 = (float2*)(X1T + (size_t)cg * SETSTR);
  float2* P1 = P0 + (size_t)cg * MAPSZ;

  spectrum_kernel<<<dim3(32), dim3(576), 0, stream>>>(sig, spec);
  prep_x<<<dim3((8192 * 52 + 255) / 256), dim3(256), 0, stream>>>(x, xs);
  pad_m<<<dim3(256), dim3(256), 0, stream>>>(ms);

  const float scale = 1.f / 16.f;  // s = 4 squarings
  for (int c0 = 0; c0 < 16; c0 += cg) {
    int g = (16 - c0 < cg) ? (16 - c0) : cg;
    buildBX<<<dim3(1296, g), dim3(256), 0, stream>>>(spec, Bst, X0, c0, scale);
    transpose4<<<dim3(9, 9, g), dim3(256), 0, stream>>>(X0, X0T);
    __hip_bfloat16 *xr = X0, *xt = X0T, *yr = X1, *yt = X1T;
    // Horner (Taylor order 3): X <- I + (B*X)/k, k=2..1. Only DT consumed until k=1.
    for (int k = 2; k >= 1; --k) {
      int wf = (k == 1) ? 3 : 2;
      cgemm_mfma<<<dim3(15 * g), dim3(512), 0, stream>>>(Bst, xt, yr, yt,
                                                         1.f / (float)k, 1.f, wf);
      __hip_bfloat16* tmp;
      tmp = xr; xr = yr; yr = tmp;
      tmp = xt; xt = yt; yt = tmp;
    }
    // 4 squarings; last one only needs row-major output (feeds passA)
    for (int t8 = 0; t8 < 4; ++t8) {
      int wf = (t8 == 3) ? 1 : 3;
      cgemm_mfma<<<dim3(15 * g), dim3(512), 0, stream>>>(xr, xt, yr, yt, 1.f, 0.f, wf);
      __hip_bfloat16* tmp;
      tmp = xr; xr = yr; yr = tmp;
      tmp = xt; xt = yt; yt = tmp;
    }
    passA<<<dim3(400, g), dim3(256), 0, stream>>>(xr, P0);
    passB<<<dim3(400, g), dim3(256), 0, stream>>>(P0, P1);
    passC<<<dim3(400, g), dim3(256), 0, stream>>>(P1, P0);
    passD<<<dim3(400, g), dim3(256), 0, stream>>>(P0, ms, c0);
  }

  out_mfma<<<dim3(32, 64), dim3(512), 0, stream>>>(xs, ms, out);
}

// Round 15
// 567.234 us; speedup vs baseline: 1.6158x; 1.1743x over previous
//
#include <hip/hip_runtime.h>
#include <hip/hip_bf16.h>
#include <math.h>

#define TAU 6.283185307179586f
#define NK 576                    // matrix dimension (K always exact: 18*32)
#define NPAD 640                  // padded row count for 128-row tiles
#define PLN ((size_t)NPAD * NK)   // elems per padded plane = 368640
#define SETSTR ((size_t)4 * PLN)  // elems per 4-plane split set
#define MAPSZ 102400              // 16*16*20*20
#define KOUT 416                  // padded K for output gemm (13*32)
#define XPL ((size_t)8192 * KOUT)
#define MPL ((size_t)4096 * KOUT)

typedef __attribute__((ext_vector_type(8))) short short8;
typedef __attribute__((ext_vector_type(4))) short short4v;
typedef __attribute__((ext_vector_type(4))) float f32x4;

__device__ inline void bsplit(float v, __hip_bfloat16& h, __hip_bfloat16& l) {
  h = __float2bfloat16(v);
  l = __float2bfloat16(v - __bfloat162float(h));
}
__device__ inline short braw(__hip_bfloat16 b) { return *reinterpret_cast<short*>(&b); }

__device__ inline void gld16(const void* g, const void* l) {
  __builtin_amdgcn_global_load_lds((const __attribute__((address_space(1))) unsigned*)g,
                                   (__attribute__((address_space(3))) unsigned*)l, 16, 0, 0);
}

#define MFMA16(a, b, c) __builtin_amdgcn_mfma_f32_16x16x32_bf16(a, b, c, 0, 0, 0)

// ---------------- Stage 1: signal -> spectrum ----------------
__device__ inline void dft24(const float2* in, float2* out, int t, float sgn, bool firstAxis) {
  int r = t / 24, c = t % 24;
  int kk = firstAxis ? r : c;
  float2 acc = make_float2(0.f, 0.f);
  for (int n = 0; n < 24; ++n) {
    float ang = sgn * (TAU / 24.f) * (float)((kk * n) % 24);
    float s, co;
    sincosf(ang, &s, &co);
    float2 v = firstAxis ? in[n * 24 + c] : in[r * 24 + n];
    acc.x += v.x * co - v.y * s;
    acc.y += v.x * s + v.y * co;
  }
  out[t] = acc;
}

__global__ void spectrum_kernel(const float* __restrict__ sig, float2* __restrict__ spec) {
  __shared__ float2 b0[576];
  __shared__ float2 b1[576];
  int f = blockIdx.x;
  int t = threadIdx.x;
  int r = t / 24, c = t % 24;
  b0[t] = make_float2(sig[f * 576 + t], 0.f);
  __syncthreads();
  dft24(b0, b1, t, -1.f, false); __syncthreads();
  dft24(b1, b0, t, -1.f, true);  __syncthreads();
  {
    int p2 = (r + 12) % 24 - 11;
    int q2 = (c + 12) % 24 - 11;
    float rr = (float)(1 + p2 * p2 + q2 * q2) * 5.f;
    float2 v = b0[t];
    b0[t] = make_float2(v.x / rr, v.y / rr);
  }
  __syncthreads();
  dft24(b0, b1, t, +1.f, false); __syncthreads();
  dft24(b1, b0, t, +1.f, true);  __syncthreads();
  {
    float winr = 0.5f * (1.f - cosf(TAU * (float)r / 24.f));
    float winc = 0.5f * (1.f - cosf(TAU * (float)c / 24.f));
    float w = winr * winc * (1.f / 576.f);
    float2 v = b0[t];
    b0[t] = make_float2(v.x * w, v.y * w);
  }
  __syncthreads();
  dft24(b0, b1, t, -1.f, false); __syncthreads();
  dft24(b1, b0, t, -1.f, true);  __syncthreads();
  int p = (r + 12) % 24, q = (c + 12) % 24;
  spec[f * 576 + p * 24 + q] = b0[t];
}

// ---------------- Stage 2: build split B and X0 = I + B/3 ----------------
__global__ void buildBX(const float2* __restrict__ spec, __hip_bfloat16* __restrict__ B,
                        __hip_bfloat16* __restrict__ X0, int c0, float scale) {
  int idx = blockIdx.x * 256 + threadIdx.x;   // 0..331775 (row*576+col, row<576)
  int cl = blockIdx.y;
  int c = c0 + cl;
  int row = idx / NK, col = idx % NK;
  int i = row / 24, j = row % 24, a = col / 24, b = col % 24;
  int u = 11 - i + a, v = 11 - j + b;
  float br = 0.f, bi = 0.f;
  if (u >= 0 && u < 24 && v >= 0 && v < 24) {
    float2 s0 = spec[(c * 2 + 0) * 576 + u * 24 + v];
    float2 s1 = spec[(c * 2 + 1) * 576 + u * 24 + v];
    float kx = (float)(a - 11), ky = (float)(b - 11);
    float xr = s0.x * kx + s1.x * ky;
    float xi = s0.y * kx + s1.y * ky;
    br = xi * scale;
    bi = -xr * scale;
  }
  size_t off = (size_t)cl * SETSTR + idx;
  __hip_bfloat16 h, l;
  bsplit(br, h, l); B[off] = h; B[off + PLN] = l;
  bsplit(bi, h, l); B[off + 2 * PLN] = h; B[off + 3 * PLN] = l;
  float d = (row == col) ? 1.f : 0.f;
  bsplit(br * (1.f / 3.f) + d, h, l); X0[off] = h; X0[off + PLN] = l;
  bsplit(bi * (1.f / 3.f), h, l);     X0[off + 2 * PLN] = h; X0[off + 3 * PLN] = l;
}

// ---------------- transpose the 4 split planes ----------------
__global__ __launch_bounds__(256) void transpose4(const __hip_bfloat16* __restrict__ src,
                                                  __hip_bfloat16* __restrict__ dst) {
  __shared__ __hip_bfloat16 tile[64][65];
  int cl = blockIdx.z;
  size_t off = (size_t)cl * SETSTR;
  int rB = blockIdx.y * 64, cB = blockIdx.x * 64;
  int tx = threadIdx.x & 63, ty = threadIdx.x >> 6;
  for (int p = 0; p < 4; ++p) {
    for (int li = 0; li < 16; ++li) {
      int r = ty * 16 + li;
      tile[r][tx] = src[off + (size_t)p * PLN + (size_t)(rB + r) * NK + cB + tx];
    }
    __syncthreads();
    for (int li = 0; li < 16; ++li) {
      int r = ty * 16 + li;
      dst[off + (size_t)p * PLN + (size_t)(cB + r) * NK + rB + tx] = tile[tx][r];
    }
    __syncthreads();
  }
}

// ---------------- Stage 3: batched split-complex MFMA GEMM, 128x192 tile ----------------
// (round-10 best-measured config: ~88 us/dispatch ~ 834 TF, the 2-barrier-structure ceiling)
__global__ __launch_bounds__(512, 2) void cgemm_mfma(
    const __hip_bfloat16* __restrict__ A, const __hip_bfloat16* __restrict__ BT,
    __hip_bfloat16* __restrict__ D, __hip_bfloat16* __restrict__ DT,
    float alpha, float delta, int wf) {
  __shared__ char lds[2][81920];   // per buf: A planes @0 (4*8192), B planes @32768 (4*12288)
  const int t = threadIdx.x;
  const int lane = t & 63;
  const int wid = t >> 6;
  const int wm = wid >> 2, wn = wid & 3;          // 2 x 4 waves, wave tile 64x48
  int p0 = blockIdx.x;
  int cl, tile;
  if (gridDim.x == 240) {
    int idx = p0 >> 3;
    cl = (p0 & 7) + 8 * (idx / 15);
    tile = idx % 15;
  } else {
    cl = p0 / 15;
    tile = p0 % 15;
  }
  const int rowBase = (tile / 3) * 128, colBase = (tile % 3) * 192;
  const size_t chOff = (size_t)cl * SETSTR;
  const __hip_bfloat16* Ab = A + chOff;
  const __hip_bfloat16* Bb = BT + chOff;

  size_t gA[4], gB[6];
  int ldsA[4], ldsB[6];
#pragma unroll
  for (int i = 0; i < 4; ++i) {
    int cid = i * 512 + t;                 // 0..2047
    int pp = cid >> 9, r = (cid >> 2) & 127, cp = cid & 3;
    int cg = cp ^ ((r >> 1) & 3);
    gA[i] = (size_t)pp * PLN + (size_t)(rowBase + r) * NK + cg * 8;
    ldsA[i] = cid * 16;
  }
#pragma unroll
  for (int i = 0; i < 6; ++i) {
    int cid = i * 512 + t;                 // 0..3071
    int pp = cid / 768, rem = cid % 768;
    int r = rem >> 2, cp = rem & 3;
    int cg = cp ^ ((r >> 1) & 3);
    gB[i] = (size_t)pp * PLN + (size_t)(colBase + r) * NK + cg * 8;
    ldsB[i] = 32768 + cid * 16;
  }
  int aoff[4], boff[3];
#pragma unroll
  for (int mi = 0; mi < 4; ++mi) {
    int ra = wm * 64 + mi * 16 + (lane & 15);
    int ch = (lane >> 4) ^ ((ra >> 1) & 3);
    aoff[mi] = (ra * 4 + ch) * 16;
  }
#pragma unroll
  for (int ni = 0; ni < 3; ++ni) {
    int cb = wn * 48 + ni * 16 + (lane & 15);
    int ch = (lane >> 4) ^ ((cb >> 1) & 3);
    boff[ni] = 32768 + (cb * 4 + ch) * 16;
  }

  f32x4 accP[4][3] = {}, accN[4][3] = {}, accI[4][3] = {};

#pragma unroll
  for (int i = 0; i < 4; ++i) gld16(Ab + gA[i], &lds[0][ldsA[i]]);
#pragma unroll
  for (int i = 0; i < 6; ++i) gld16(Bb + gB[i], &lds[0][ldsB[i]]);

#pragma unroll 1
  for (int ks = 0; ks < 18; ++ks) {
    const int cur = ks & 1;
    const int k1 = (ks + 1) * 32;
    asm volatile("s_waitcnt vmcnt(0)" ::: "memory");
    __builtin_amdgcn_sched_barrier(0);
    __builtin_amdgcn_s_barrier();
    __builtin_amdgcn_sched_barrier(0);

    short8 brh[3], brl[3], bih[3], bil[3];
#pragma unroll
    for (int ni = 0; ni < 3; ++ni) {
      const char* base = &lds[cur][boff[ni]];
      brh[ni] = *(const short8*)(base);
      brl[ni] = *(const short8*)(base + 12288);
      bih[ni] = *(const short8*)(base + 24576);
      bil[ni] = *(const short8*)(base + 36864);
    }
#pragma unroll
    for (int p = 0; p < 4; ++p) {
      short8 arh, arl, aih, ail;
      {
        const char* base = &lds[cur][aoff[p]];
        arh = *(const short8*)(base);
        arl = *(const short8*)(base + 8192);
        aih = *(const short8*)(base + 16384);
        ail = *(const short8*)(base + 24576);
      }
      if (ks < 17) {
        if (p == 0) {
          gld16(Ab + gA[0] + k1, &lds[cur ^ 1][ldsA[0]]);
          gld16(Ab + gA[1] + k1, &lds[cur ^ 1][ldsA[1]]);
          gld16(Ab + gA[2] + k1, &lds[cur ^ 1][ldsA[2]]);
          gld16(Ab + gA[3] + k1, &lds[cur ^ 1][ldsA[3]]);
        } else if (p == 1) {
          gld16(Bb + gB[0] + k1, &lds[cur ^ 1][ldsB[0]]);
          gld16(Bb + gB[1] + k1, &lds[cur ^ 1][ldsB[1]]);
          gld16(Bb + gB[2] + k1, &lds[cur ^ 1][ldsB[2]]);
        } else if (p == 2) {
          gld16(Bb + gB[3] + k1, &lds[cur ^ 1][ldsB[3]]);
          gld16(Bb + gB[4] + k1, &lds[cur ^ 1][ldsB[4]]);
          gld16(Bb + gB[5] + k1, &lds[cur ^ 1][ldsB[5]]);
        }
      }
      __builtin_amdgcn_s_setprio(1);
#pragma unroll
      for (int ni = 0; ni < 3; ++ni) {
        accP[p][ni] = MFMA16(arh, brh[ni], accP[p][ni]);
        accP[p][ni] = MFMA16(arh, brl[ni], accP[p][ni]);
        accP[p][ni] = MFMA16(arl, brh[ni], accP[p][ni]);
        accN[p][ni] = MFMA16(aih, bih[ni], accN[p][ni]);
        accN[p][ni] = MFMA16(aih, bil[ni], accN[p][ni]);
        accN[p][ni] = MFMA16(ail, bih[ni], accN[p][ni]);
        accI[p][ni] = MFMA16(arh, bih[ni], accI[p][ni]);
        accI[p][ni] = MFMA16(arh, bil[ni], accI[p][ni]);
        accI[p][ni] = MFMA16(arl, bih[ni], accI[p][ni]);
        accI[p][ni] = MFMA16(aih, brh[ni], accI[p][ni]);
        accI[p][ni] = MFMA16(aih, brl[ni], accI[p][ni]);
        accI[p][ni] = MFMA16(ail, brh[ni], accI[p][ni]);
      }
      __builtin_amdgcn_s_setprio(0);
    }
    __builtin_amdgcn_sched_barrier(0);
  }

  __hip_bfloat16* Dp = D + chOff;
  __hip_bfloat16* Tp = DT + chOff;
#pragma unroll
  for (int mi = 0; mi < 4; ++mi)
#pragma unroll
    for (int ni = 0; ni < 3; ++ni) {
      int rb = rowBase + wm * 64 + mi * 16 + (lane >> 4) * 4;
      int cc = colBase + wn * 48 + ni * 16 + (lane & 15);
      if (rb >= NK) continue;
      short hR[4], lR[4], hI[4], lI[4];
#pragma unroll
      for (int j = 0; j < 4; ++j) {
        float vR = alpha * (accP[mi][ni][j] - accN[mi][ni][j]) + ((rb + j == cc) ? delta : 0.f);
        float vI = alpha * accI[mi][ni][j];
        __hip_bfloat16 h, l;
        bsplit(vR, h, l); hR[j] = braw(h); lR[j] = braw(l);
        bsplit(vI, h, l); hI[j] = braw(h); lI[j] = braw(l);
      }
      if (wf & 1) {
#pragma unroll
        for (int j = 0; j < 4; ++j) {
          size_t o = (size_t)(rb + j) * NK + cc;
          *(short*)&Dp[o] = hR[j];
          *(short*)&Dp[PLN + o] = lR[j];
          *(short*)&Dp[2 * PLN + o] = hI[j];
          *(short*)&Dp[3 * PLN + o] = lI[j];
        }
      }
      if (wf & 2) {
        size_t o = (size_t)cc * NK + rb;
        short4v vR4 = {hR[0], hR[1], hR[2], hR[3]};
        short4v vL4 = {lR[0], lR[1], lR[2], lR[3]};
        short4v vI4 = {hI[0], hI[1], hI[2], hI[3]};
        short4v vJ4 = {lI[0], lI[1], lI[2], lI[3]};
        *(short4v*)&Tp[o] = vR4;
        *(short4v*)&Tp[PLN + o] = vL4;
        *(short4v*)&Tp[2 * PLN + o] = vI4;
        *(short4v*)&Tp[3 * PLN + o] = vJ4;
      }
    }
}

// ---------------- Stage 4: fused separable DFTs ----------------
// passAB: for fixed output (p,q), do the v'-DFT (gather from T) then u'-DFT via LDS.
__global__ __launch_bounds__(448) void passAB(const __hip_bfloat16* __restrict__ X,
                                              float2* __restrict__ P) {
  __shared__ float2 tw[20];
  __shared__ float2 lA[400];
  int t = threadIdx.x;
  if (t < 20) {
    float s, c;
    sincosf((TAU / 20.f) * (float)t, &s, &c);
    tw[t] = make_float2(c, s);
  }
  __syncthreads();
  int cl = blockIdx.y;
  int pq = blockIdx.x;           // p*16+q
  int p = pq >> 4, q = pq & 15;
  int pp = (p + 7) & 15;
  int qq = (q + 7) & 15;
  int row = (pp + 5) * 24 + (qq + 5);
  const __hip_bfloat16* tb = X + (size_t)cl * SETSTR;
  if (t < 400) {
    int v = t % 20, u = t / 20;
    int aa = (u + 9) % 20 + 3;
    float2 acc = make_float2(0.f, 0.f);
    for (int vp = 0; vp < 20; ++vp) {
      int vv = (vp + 9) % 20;
      size_t o = (size_t)row * NK + aa * 24 + (vv + 3);
      float xr = __bfloat162float(tb[o]) + __bfloat162float(tb[PLN + o]);
      float xi = __bfloat162float(tb[2 * PLN + o]) + __bfloat162float(tb[3 * PLN + o]);
      float2 w = tw[(v * vp) % 20];
      acc.x += xr * w.x - xi * w.y;
      acc.y += xr * w.y + xi * w.x;
    }
    lA[t] = acc;
  }
  __syncthreads();
  if (t < 400) {
    int v = t % 20, u = t / 20;
    float2 acc = make_float2(0.f, 0.f);
    for (int up = 0; up < 20; ++up) {
      float2 val = lA[up * 20 + v];
      float2 w = tw[(u * up) % 20];
      acc.x += val.x * w.x - val.y * w.y;
      acc.y += val.x * w.y + val.y * w.x;
    }
    P[(size_t)cl * MAPSZ + pq * 400 + t] = acc;
  }
}

// passCD: for fixed (u,v), do the q'-DFT then p'-DFT via LDS; write bf16 m (hi only).
__global__ __launch_bounds__(256) void passCD(const float2* __restrict__ Pin,
                                              __hip_bfloat16* __restrict__ ms, int c0) {
  __shared__ float2 tw[16];
  __shared__ float2 lC[256];
  int t = threadIdx.x;
  if (t < 16) {
    float s, c;
    sincosf(-(TAU / 16.f) * (float)t, &s, &c);
    tw[t] = make_float2(c, s);
  }
  __syncthreads();
  int cl = blockIdx.y;
  int c = c0 + cl;
  int uv = blockIdx.x;           // u*20+v
  const float2* in = Pin + (size_t)cl * MAPSZ;
  int p = t >> 4, q = t & 15;
  float2 acc = make_float2(0.f, 0.f);
  for (int qp = 0; qp < 16; ++qp) {
    float2 val = in[p * 6400 + qp * 400 + uv];
    float2 w = tw[(q * qp) & 15];
    acc.x += val.x * w.x - val.y * w.y;
    acc.y += val.x * w.y + val.y * w.x;
  }
  lC[t] = acc;
  __syncthreads();
  float r = 0.f;
  for (int pp = 0; pp < 16; ++pp) {
    float2 val = lC[pp * 16 + q];
    float2 w = tw[(p * pp) & 15];
    r += val.x * w.x - val.y * w.y;
  }
  r *= (1.f / 400.f);
  int n = c * 256 + t;
  ms[(size_t)n * KOUT + uv] = __float2bfloat16(r);
}

// zero the k in [400,416) pad of the m plane (hi only)
__global__ void pad_m(__hip_bfloat16* __restrict__ ms) {
  int idx = blockIdx.x * 256 + threadIdx.x;   // 4096*16
  int n = idx >> 4;
  int k = 400 + (idx & 15);
  ms[(size_t)n * KOUT + k] = __float2bfloat16(0.f);
}

// convert x (8192x400 f32) to bf16 padded [8192][KOUT] (hi only)
__global__ void prep_x(const float* __restrict__ x, __hip_bfloat16* __restrict__ xs) {
  int idx = blockIdx.x * 256 + threadIdx.x;   // 8192*52
  if (idx >= 8192 * 52) return;
  int b = idx / 52, c8 = idx % 52;
  int k = c8 * 8;
  short8 hh = {};
  if (k < 400) {
    const float4* xp = (const float4*)(x + (size_t)b * 400 + k);
    float4 v0 = xp[0], v1 = xp[1];
    float vals[8] = {v0.x, v0.y, v0.z, v0.w, v1.x, v1.y, v1.z, v1.w};
#pragma unroll
    for (int i = 0; i < 8; ++i) hh[i] = braw(__float2bfloat16(vals[i]));
  }
  *(short8*)(xs + (size_t)b * KOUT + k) = hh;
}

// ---------------- Stage 5: output GEMM, x bf16 x m bf16, 128x128 tile ----------------
__global__ __launch_bounds__(512, 2) void out_mfma(
    const __hip_bfloat16* __restrict__ xs, const __hip_bfloat16* __restrict__ ms,
    float* __restrict__ Y) {
  __shared__ char lds[2][16384];   // A @0 (8192), B @8192
  const int t = threadIdx.x;
  const int lane = t & 63;
  const int wid = t >> 6;
  const int wm = wid >> 2, wn = wid & 3;
  const int rowBase = blockIdx.y * 128, colBase = blockIdx.x * 128;

  size_t gA1, gB1;
  int ldsA1, ldsB1;
  {
    int cid = t;                          // 0..511
    int r = (cid >> 2) & 127, cp = cid & 3;
    int cg = cp ^ ((r >> 1) & 3);
    gA1 = (size_t)(rowBase + r) * KOUT + cg * 8;
    gB1 = (size_t)(colBase + r) * KOUT + cg * 8;
    ldsA1 = cid * 16;
    ldsB1 = 8192 + cid * 16;
  }
  int aoff[4], boff[2];
#pragma unroll
  for (int mi = 0; mi < 4; ++mi) {
    int ra = wm * 64 + mi * 16 + (lane & 15);
    int ch = (lane >> 4) ^ ((ra >> 1) & 3);
    aoff[mi] = (ra * 4 + ch) * 16;
  }
#pragma unroll
  for (int ni = 0; ni < 2; ++ni) {
    int cb = wn * 32 + ni * 16 + (lane & 15);
    int ch = (lane >> 4) ^ ((cb >> 1) & 3);
    boff[ni] = 8192 + (cb * 4 + ch) * 16;
  }

  f32x4 acc[4][2] = {};

  gld16(xs + gA1, &lds[0][ldsA1]);
  gld16(ms + gB1, &lds[0][ldsB1]);

#pragma unroll 1
  for (int ks = 0; ks < 13; ++ks) {
    int cur = ks & 1;
    int k1 = (ks + 1) * 32;
    asm volatile("s_waitcnt vmcnt(0)" ::: "memory");
    __builtin_amdgcn_sched_barrier(0);
    __builtin_amdgcn_s_barrier();
    __builtin_amdgcn_sched_barrier(0);
    short8 bh[2];
#pragma unroll
    for (int ni = 0; ni < 2; ++ni)
      bh[ni] = *(const short8*)(&lds[cur][boff[ni]]);
#pragma unroll
    for (int mi = 0; mi < 4; ++mi) {
      short8 ah = *(const short8*)(&lds[cur][aoff[mi]]);
      if (ks < 12) {
        if (mi == 0) gld16(xs + gA1 + k1, &lds[cur ^ 1][ldsA1]);
        else if (mi == 1) gld16(ms + gB1 + k1, &lds[cur ^ 1][ldsB1]);
      }
      __builtin_amdgcn_s_setprio(1);
#pragma unroll
      for (int ni = 0; ni < 2; ++ni)
        acc[mi][ni] = MFMA16(ah, bh[ni], acc[mi][ni]);
      __builtin_amdgcn_s_setprio(0);
    }
    __builtin_amdgcn_sched_barrier(0);
  }

#pragma unroll
  for (int mi = 0; mi < 4; ++mi)
#pragma unroll
    for (int ni = 0; ni < 2; ++ni) {
      int rb = rowBase + wm * 64 + mi * 16 + (lane >> 4) * 4;
      int cc = colBase + wn * 32 + ni * 16 + (lane & 15);
#pragma unroll
      for (int j = 0; j < 4; ++j)
        Y[(size_t)(rb + j) * 4096 + cc] = acc[mi][ni][j];
    }
}

// ---------------- Launcher ----------------
extern "C" void kernel_launch(void* const* d_in, const int* in_sizes, int n_in,
                              void* d_out, int out_size, void* d_ws, size_t ws_size,
                              hipStream_t stream) {
  const float* x = (const float*)d_in[0];     // (8192,1,20,20)
  const float* sig = (const float*)d_in[1];   // (16,2,24,24)
  float* out = (float*)d_out;                 // (8192,16,16,16)
  char* ws = (char*)d_ws;

  const size_t specBytes = 32ull * 576 * sizeof(float2);
  const size_t xsBytes = XPL * 2;                       // one bf16 plane
  const size_t msBytes = MPL * 2;                       // one bf16 plane
  const size_t fixed = specBytes + xsBytes + msBytes;
  const size_t setB = SETSTR * 2;                       // bytes per split set
  const size_t perCh = 5 * setB + (size_t)MAPSZ * 8;    // B, X0, X0T, X1, X1T + P0

  int cg = 1;
  if (ws_size > fixed) {
    size_t av = (ws_size - fixed) / perCh;
    cg = (av < 1) ? 1 : (av > 16 ? 16 : (int)av);
  }

  float2* spec = (float2*)ws;
  __hip_bfloat16* xs = (__hip_bfloat16*)(ws + specBytes);
  __hip_bfloat16* ms = (__hip_bfloat16*)(ws + specBytes + xsBytes);
  __hip_bfloat16* Bst = (__hip_bfloat16*)(ws + fixed);
  __hip_bfloat16* X0 = Bst + (size_t)cg * SETSTR;
  __hip_bfloat16* X0T = X0 + (size_t)cg * SETSTR;
  __hip_bfloat16* X1 = X0T + (size_t)cg * SETSTR;
  __hip_bfloat16* X1T = X1 + (size_t)cg * SETSTR;
  float2* P0 = (float2*)(X1T + (size_t)cg * SETSTR);

  spectrum_kernel<<<dim3(32), dim3(576), 0, stream>>>(sig, spec);
  prep_x<<<dim3((8192 * 52 + 255) / 256), dim3(256), 0, stream>>>(x, xs);
  pad_m<<<dim3(256), dim3(256), 0, stream>>>(ms);

  const float scale = 1.f / 8.f;  // s = 3 squarings
  for (int c0 = 0; c0 < 16; c0 += cg) {
    int g = (16 - c0 < cg) ? (16 - c0) : cg;
    buildBX<<<dim3(1296, g), dim3(256), 0, stream>>>(spec, Bst, X0, c0, scale);
    transpose4<<<dim3(9, 9, g), dim3(256), 0, stream>>>(X0, X0T);
    __hip_bfloat16 *xr = X0, *xt = X0T, *yr = X1, *yt = X1T;
    // Horner (Taylor order 3): X <- I + (B*X)/k, k=2..1. Only DT consumed until k=1.
    for (int k = 2; k >= 1; --k) {
      int wf = (k == 1) ? 3 : 2;
      cgemm_mfma<<<dim3(15 * g), dim3(512), 0, stream>>>(Bst, xt, yr, yt,
                                                         1.f / (float)k, 1.f, wf);
      __hip_bfloat16* tmp;
      tmp = xr; xr = yr; yr = tmp;
      tmp = xt; xt = yt; yt = tmp;
    }
    // 3 squarings; last one only needs row-major output (feeds passAB)
    for (int t8 = 0; t8 < 3; ++t8) {
      int wf = (t8 == 2) ? 1 : 3;
      cgemm_mfma<<<dim3(15 * g), dim3(512), 0, stream>>>(xr, xt, yr, yt, 1.f, 0.f, wf);
      __hip_bfloat16* tmp;
      tmp = xr; xr = yr; yr = tmp;
      tmp = xt; xt = yt; yt = tmp;
    }
    passAB<<<dim3(256, g), dim3(448), 0, stream>>>(xr, P0);
    passCD<<<dim3(400, g), dim3(256), 0, stream>>>(P0, ms, c0);
  }

  out_mfma<<<dim3(32, 64), dim3(512), 0, stream>>>(xs, ms, out);
}

// Round 16
// 532.538 us; speedup vs baseline: 1.7210x; 1.0652x over previous
//
#include <hip/hip_runtime.h>
#include <hip/hip_bf16.h>
#include <math.h>

#define TAU 6.283185307179586f
#define NK 576                    // matrix dimension (K always exact: 18*32)
#define NPAD 640                  // padded row count for 128-row tiles
#define PLN ((size_t)NPAD * NK)   // elems per padded plane = 368640
#define SETSTR ((size_t)4 * PLN)  // elems per 4-plane split set
#define MAPSZ 102400              // 16*16*20*20
#define KOUT 416                  // padded K for output gemm (13*32)
#define XPL ((size_t)8192 * KOUT)
#define MPL ((size_t)4096 * KOUT)

typedef __attribute__((ext_vector_type(8))) short short8;
typedef __attribute__((ext_vector_type(4))) short short4v;
typedef __attribute__((ext_vector_type(4))) float f32x4;

__device__ inline void bsplit(float v, __hip_bfloat16& h, __hip_bfloat16& l) {
  h = __float2bfloat16(v);
  l = __float2bfloat16(v - __bfloat162float(h));
}
__device__ inline short braw(__hip_bfloat16 b) { return *reinterpret_cast<short*>(&b); }
__device__ inline float b2f(__hip_bfloat16 b) { return __bfloat162float(b); }

__device__ inline void gld16(const void* g, const void* l) {
  __builtin_amdgcn_global_load_lds((const __attribute__((address_space(1))) unsigned*)g,
                                   (__attribute__((address_space(3))) unsigned*)l, 16, 0, 0);
}

#define MFMA16(a, b, c) __builtin_amdgcn_mfma_f32_16x16x32_bf16(a, b, c, 0, 0, 0)

// ---------------- Stage 1: signal -> spectrum ----------------
__device__ inline void dft24(const float2* in, float2* out, int t, float sgn, bool firstAxis) {
  int r = t / 24, c = t % 24;
  int kk = firstAxis ? r : c;
  float2 acc = make_float2(0.f, 0.f);
  for (int n = 0; n < 24; ++n) {
    float ang = sgn * (TAU / 24.f) * (float)((kk * n) % 24);
    float s, co;
    sincosf(ang, &s, &co);
    float2 v = firstAxis ? in[n * 24 + c] : in[r * 24 + n];
    acc.x += v.x * co - v.y * s;
    acc.y += v.x * s + v.y * co;
  }
  out[t] = acc;
}

__global__ void spectrum_kernel(const float* __restrict__ sig, float2* __restrict__ spec) {
  __shared__ float2 b0[576];
  __shared__ float2 b1[576];
  int f = blockIdx.x;
  int t = threadIdx.x;
  int r = t / 24, c = t % 24;
  b0[t] = make_float2(sig[f * 576 + t], 0.f);
  __syncthreads();
  dft24(b0, b1, t, -1.f, false); __syncthreads();
  dft24(b1, b0, t, -1.f, true);  __syncthreads();
  {
    int p2 = (r + 12) % 24 - 11;
    int q2 = (c + 12) % 24 - 11;
    float rr = (float)(1 + p2 * p2 + q2 * q2) * 5.f;
    float2 v = b0[t];
    b0[t] = make_float2(v.x / rr, v.y / rr);
  }
  __syncthreads();
  dft24(b0, b1, t, +1.f, false); __syncthreads();
  dft24(b1, b0, t, +1.f, true);  __syncthreads();
  {
    float winr = 0.5f * (1.f - cosf(TAU * (float)r / 24.f));
    float winc = 0.5f * (1.f - cosf(TAU * (float)c / 24.f));
    float w = winr * winc * (1.f / 576.f);
    float2 v = b0[t];
    b0[t] = make_float2(v.x * w, v.y * w);
  }
  __syncthreads();
  dft24(b0, b1, t, -1.f, false); __syncthreads();
  dft24(b1, b0, t, -1.f, true);  __syncthreads();
  int p = (r + 12) % 24, q = (c + 12) % 24;
  spec[f * 576 + p * 24 + q] = b0[t];
}

// ---------------- Stage 2: build split X = A/4 ----------------
__global__ void buildBX(const float2* __restrict__ spec, __hip_bfloat16* __restrict__ X,
                        int c0, float scale) {
  int idx = blockIdx.x * 256 + threadIdx.x;   // 0..331775 (row*576+col, row<576)
  int cl = blockIdx.y;
  int c = c0 + cl;
  int row = idx / NK, col = idx % NK;
  int i = row / 24, j = row % 24, a = col / 24, b = col % 24;
  int u = 11 - i + a, v = 11 - j + b;
  float br = 0.f, bi = 0.f;
  if (u >= 0 && u < 24 && v >= 0 && v < 24) {
    float2 s0 = spec[(c * 2 + 0) * 576 + u * 24 + v];
    float2 s1 = spec[(c * 2 + 1) * 576 + u * 24 + v];
    float kx = (float)(a - 11), ky = (float)(b - 11);
    float xr = s0.x * kx + s1.x * ky;
    float xi = s0.y * kx + s1.y * ky;
    br = xi * scale;
    bi = -xr * scale;
  }
  size_t off = (size_t)cl * SETSTR + idx;
  __hip_bfloat16 h, l;
  bsplit(br, h, l); X[off] = h; X[off + PLN] = l;
  bsplit(bi, h, l); X[off + 2 * PLN] = h; X[off + 3 * PLN] = l;
}

// ---------------- transpose the 4 split planes ----------------
__global__ __launch_bounds__(256) void transpose4(const __hip_bfloat16* __restrict__ src,
                                                  __hip_bfloat16* __restrict__ dst) {
  __shared__ __hip_bfloat16 tile[64][65];
  int cl = blockIdx.z;
  size_t off = (size_t)cl * SETSTR;
  int rB = blockIdx.y * 64, cB = blockIdx.x * 64;
  int tx = threadIdx.x & 63, ty = threadIdx.x >> 6;
  for (int p = 0; p < 4; ++p) {
    for (int li = 0; li < 16; ++li) {
      int r = ty * 16 + li;
      tile[r][tx] = src[off + (size_t)p * PLN + (size_t)(rB + r) * NK + cB + tx];
    }
    __syncthreads();
    for (int li = 0; li < 16; ++li) {
      int r = ty * 16 + li;
      dst[off + (size_t)p * PLN + (size_t)(cB + r) * NK + rB + tx] = tile[tx][r];
    }
    __syncthreads();
  }
}

// ---------------- buildC: CT = I/2 + XT/6 + X2T/24 (elementwise, split) ----------------
__global__ void buildC(const __hip_bfloat16* __restrict__ XT,
                       const __hip_bfloat16* __restrict__ X2T,
                       __hip_bfloat16* __restrict__ CT) {
  int idx = blockIdx.x * 256 + threadIdx.x;   // 0..331775
  int cl = blockIdx.y;
  size_t off = (size_t)cl * SETSTR + idx;
  int row = idx / NK, col = idx % NK;
  float xr = b2f(XT[off]) + b2f(XT[off + PLN]);
  float xi = b2f(XT[off + 2 * PLN]) + b2f(XT[off + 3 * PLN]);
  float x2r = b2f(X2T[off]) + b2f(X2T[off + PLN]);
  float x2i = b2f(X2T[off + 2 * PLN]) + b2f(X2T[off + 3 * PLN]);
  float d = (row == col) ? 0.5f : 0.f;
  float cr = d + xr * (1.f / 6.f) + x2r * (1.f / 24.f);
  float ci = xi * (1.f / 6.f) + x2i * (1.f / 24.f);
  __hip_bfloat16 h, l;
  bsplit(cr, h, l); CT[off] = h; CT[off + PLN] = l;
  bsplit(ci, h, l); CT[off + 2 * PLN] = h; CT[off + 3 * PLN] = l;
}

// ---------------- Stage 3: batched split-complex MFMA GEMM, 128x192 tile ----------------
// D = alpha*(A*B) + delta*I + E (E optional).  A row-major split; B as BT [n][k].
// wf bit0: write D; bit1: write DT.
__global__ __launch_bounds__(512, 2) void cgemm_mfma(
    const __hip_bfloat16* __restrict__ A, const __hip_bfloat16* __restrict__ BT,
    __hip_bfloat16* __restrict__ D, __hip_bfloat16* __restrict__ DT,
    const __hip_bfloat16* __restrict__ E,
    float alpha, float delta, int wf) {
  __shared__ char lds[2][81920];   // per buf: A planes @0 (4*8192), B planes @32768 (4*12288)
  const int t = threadIdx.x;
  const int lane = t & 63;
  const int wid = t >> 6;
  const int wm = wid >> 2, wn = wid & 3;          // 2 x 4 waves, wave tile 64x48
  int p0 = blockIdx.x;
  int cl, tile;
  if (gridDim.x == 240) {
    int idx = p0 >> 3;
    cl = (p0 & 7) + 8 * (idx / 15);
    tile = idx % 15;
  } else {
    cl = p0 / 15;
    tile = p0 % 15;
  }
  const int rowBase = (tile / 3) * 128, colBase = (tile % 3) * 192;
  const size_t chOff = (size_t)cl * SETSTR;
  const __hip_bfloat16* Ab = A + chOff;
  const __hip_bfloat16* Bb = BT + chOff;

  size_t gA[4], gB[6];
  int ldsA[4], ldsB[6];
#pragma unroll
  for (int i = 0; i < 4; ++i) {
    int cid = i * 512 + t;                 // 0..2047
    int pp = cid >> 9, r = (cid >> 2) & 127, cp = cid & 3;
    int cg = cp ^ ((r >> 1) & 3);
    gA[i] = (size_t)pp * PLN + (size_t)(rowBase + r) * NK + cg * 8;
    ldsA[i] = cid * 16;
  }
#pragma unroll
  for (int i = 0; i < 6; ++i) {
    int cid = i * 512 + t;                 // 0..3071
    int pp = cid / 768, rem = cid % 768;
    int r = rem >> 2, cp = rem & 3;
    int cg = cp ^ ((r >> 1) & 3);
    gB[i] = (size_t)pp * PLN + (size_t)(colBase + r) * NK + cg * 8;
    ldsB[i] = 32768 + cid * 16;
  }
  int aoff[4], boff[3];
#pragma unroll
  for (int mi = 0; mi < 4; ++mi) {
    int ra = wm * 64 + mi * 16 + (lane & 15);
    int ch = (lane >> 4) ^ ((ra >> 1) & 3);
    aoff[mi] = (ra * 4 + ch) * 16;
  }
#pragma unroll
  for (int ni = 0; ni < 3; ++ni) {
    int cb = wn * 48 + ni * 16 + (lane & 15);
    int ch = (lane >> 4) ^ ((cb >> 1) & 3);
    boff[ni] = 32768 + (cb * 4 + ch) * 16;
  }

  f32x4 accP[4][3] = {}, accN[4][3] = {}, accI[4][3] = {};

#pragma unroll
  for (int i = 0; i < 4; ++i) gld16(Ab + gA[i], &lds[0][ldsA[i]]);
#pragma unroll
  for (int i = 0; i < 6; ++i) gld16(Bb + gB[i], &lds[0][ldsB[i]]);

#pragma unroll 1
  for (int ks = 0; ks < 18; ++ks) {
    const int cur = ks & 1;
    const int k1 = (ks + 1) * 32;
    asm volatile("s_waitcnt vmcnt(0)" ::: "memory");
    __builtin_amdgcn_sched_barrier(0);
    __builtin_amdgcn_s_barrier();
    __builtin_amdgcn_sched_barrier(0);

    short8 brh[3], brl[3], bih[3], bil[3];
#pragma unroll
    for (int ni = 0; ni < 3; ++ni) {
      const char* base = &lds[cur][boff[ni]];
      brh[ni] = *(const short8*)(base);
      brl[ni] = *(const short8*)(base + 12288);
      bih[ni] = *(const short8*)(base + 24576);
      bil[ni] = *(const short8*)(base + 36864);
    }
#pragma unroll
    for (int p = 0; p < 4; ++p) {
      short8 arh, arl, aih, ail;
      {
        const char* base = &lds[cur][aoff[p]];
        arh = *(const short8*)(base);
        arl = *(const short8*)(base + 8192);
        aih = *(const short8*)(base + 16384);
        ail = *(const short8*)(base + 24576);
      }
      if (ks < 17) {
        if (p == 0) {
          gld16(Ab + gA[0] + k1, &lds[cur ^ 1][ldsA[0]]);
          gld16(Ab + gA[1] + k1, &lds[cur ^ 1][ldsA[1]]);
          gld16(Ab + gA[2] + k1, &lds[cur ^ 1][ldsA[2]]);
          gld16(Ab + gA[3] + k1, &lds[cur ^ 1][ldsA[3]]);
        } else if (p == 1) {
          gld16(Bb + gB[0] + k1, &lds[cur ^ 1][ldsB[0]]);
          gld16(Bb + gB[1] + k1, &lds[cur ^ 1][ldsB[1]]);
          gld16(Bb + gB[2] + k1, &lds[cur ^ 1][ldsB[2]]);
        } else if (p == 2) {
          gld16(Bb + gB[3] + k1, &lds[cur ^ 1][ldsB[3]]);
          gld16(Bb + gB[4] + k1, &lds[cur ^ 1][ldsB[4]]);
          gld16(Bb + gB[5] + k1, &lds[cur ^ 1][ldsB[5]]);
        }
      }
      __builtin_amdgcn_s_setprio(1);
#pragma unroll
      for (int ni = 0; ni < 3; ++ni) {
        accP[p][ni] = MFMA16(arh, brh[ni], accP[p][ni]);
        accP[p][ni] = MFMA16(arh, brl[ni], accP[p][ni]);
        accP[p][ni] = MFMA16(arl, brh[ni], accP[p][ni]);
        accN[p][ni] = MFMA16(aih, bih[ni], accN[p][ni]);
        accN[p][ni] = MFMA16(aih, bil[ni], accN[p][ni]);
        accN[p][ni] = MFMA16(ail, bih[ni], accN[p][ni]);
        accI[p][ni] = MFMA16(arh, bih[ni], accI[p][ni]);
        accI[p][ni] = MFMA16(arh, bil[ni], accI[p][ni]);
        accI[p][ni] = MFMA16(arl, bih[ni], accI[p][ni]);
        accI[p][ni] = MFMA16(aih, brh[ni], accI[p][ni]);
        accI[p][ni] = MFMA16(aih, brl[ni], accI[p][ni]);
        accI[p][ni] = MFMA16(ail, brh[ni], accI[p][ni]);
      }
      __builtin_amdgcn_s_setprio(0);
    }
    __builtin_amdgcn_sched_barrier(0);
  }

  __hip_bfloat16* Dp = D + chOff;
  __hip_bfloat16* Tp = DT + chOff;
  const __hip_bfloat16* Ep = E ? (E + chOff) : nullptr;
#pragma unroll
  for (int mi = 0; mi < 4; ++mi)
#pragma unroll
    for (int ni = 0; ni < 3; ++ni) {
      int rb = rowBase + wm * 64 + mi * 16 + (lane >> 4) * 4;
      int cc = colBase + wn * 48 + ni * 16 + (lane & 15);
      if (rb >= NK) continue;
      short hR[4], lR[4], hI[4], lI[4];
#pragma unroll
      for (int j = 0; j < 4; ++j) {
        float er = 0.f, ei = 0.f;
        if (Ep) {
          size_t o = (size_t)(rb + j) * NK + cc;
          er = b2f(Ep[o]) + b2f(Ep[PLN + o]);
          ei = b2f(Ep[2 * PLN + o]) + b2f(Ep[3 * PLN + o]);
        }
        float vR = alpha * (accP[mi][ni][j] - accN[mi][ni][j]) +
                   ((rb + j == cc) ? delta : 0.f) + er;
        float vI = alpha * accI[mi][ni][j] + ei;
        __hip_bfloat16 h, l;
        bsplit(vR, h, l); hR[j] = braw(h); lR[j] = braw(l);
        bsplit(vI, h, l); hI[j] = braw(h); lI[j] = braw(l);
      }
      if (wf & 1) {
#pragma unroll
        for (int j = 0; j < 4; ++j) {
          size_t o = (size_t)(rb + j) * NK + cc;
          *(short*)&Dp[o] = hR[j];
          *(short*)&Dp[PLN + o] = lR[j];
          *(short*)&Dp[2 * PLN + o] = hI[j];
          *(short*)&Dp[3 * PLN + o] = lI[j];
        }
      }
      if (wf & 2) {
        size_t o = (size_t)cc * NK + rb;
        short4v vR4 = {hR[0], hR[1], hR[2], hR[3]};
        short4v vL4 = {lR[0], lR[1], lR[2], lR[3]};
        short4v vI4 = {hI[0], hI[1], hI[2], hI[3]};
        short4v vJ4 = {lI[0], lI[1], lI[2], lI[3]};
        *(short4v*)&Tp[o] = vR4;
        *(short4v*)&Tp[PLN + o] = vL4;
        *(short4v*)&Tp[2 * PLN + o] = vI4;
        *(short4v*)&Tp[3 * PLN + o] = vJ4;
      }
    }
}

// ---------------- Stage 4: fused separable DFTs ----------------
__global__ __launch_bounds__(448) void passAB(const __hip_bfloat16* __restrict__ X,
                                              float2* __restrict__ P) {
  __shared__ float2 tw[20];
  __shared__ float2 lA[400];
  int t = threadIdx.x;
  if (t < 20) {
    float s, c;
    sincosf((TAU / 20.f) * (float)t, &s, &c);
    tw[t] = make_float2(c, s);
  }
  __syncthreads();
  int cl = blockIdx.y;
  int pq = blockIdx.x;           // p*16+q
  int p = pq >> 4, q = pq & 15;
  int pp = (p + 7) & 15;
  int qq = (q + 7) & 15;
  int row = (pp + 5) * 24 + (qq + 5);
  const __hip_bfloat16* tb = X + (size_t)cl * SETSTR;
  if (t < 400) {
    int v = t % 20, u = t / 20;
    int aa = (u + 9) % 20 + 3;
    float2 acc = make_float2(0.f, 0.f);
    for (int vp = 0; vp < 20; ++vp) {
      int vv = (vp + 9) % 20;
      size_t o = (size_t)row * NK + aa * 24 + (vv + 3);
      float xr = b2f(tb[o]) + b2f(tb[PLN + o]);
      float xi = b2f(tb[2 * PLN + o]) + b2f(tb[3 * PLN + o]);
      float2 w = tw[(v * vp) % 20];
      acc.x += xr * w.x - xi * w.y;
      acc.y += xr * w.y + xi * w.x;
    }
    lA[t] = acc;
  }
  __syncthreads();
  if (t < 400) {
    int v = t % 20, u = t / 20;
    float2 acc = make_float2(0.f, 0.f);
    for (int up = 0; up < 20; ++up) {
      float2 val = lA[up * 20 + v];
      float2 w = tw[(u * up) % 20];
      acc.x += val.x * w.x - val.y * w.y;
      acc.y += val.x * w.y + val.y * w.x;
    }
    P[(size_t)cl * MAPSZ + pq * 400 + t] = acc;
  }
}

__global__ __launch_bounds__(256) void passCD(const float2* __restrict__ Pin,
                                              __hip_bfloat16* __restrict__ ms, int c0) {
  __shared__ float2 tw[16];
  __shared__ float2 lC[256];
  int t = threadIdx.x;
  if (t < 16) {
    float s, c;
    sincosf(-(TAU / 16.f) * (float)t, &s, &c);
    tw[t] = make_float2(c, s);
  }
  __syncthreads();
  int cl = blockIdx.y;
  int c = c0 + cl;
  int uv = blockIdx.x;           // u*20+v
  const float2* in = Pin + (size_t)cl * MAPSZ;
  int p = t >> 4, q = t & 15;
  float2 acc = make_float2(0.f, 0.f);
  for (int qp = 0; qp < 16; ++qp) {
    float2 val = in[p * 6400 + qp * 400 + uv];
    float2 w = tw[(q * qp) & 15];
    acc.x += val.x * w.x - val.y * w.y;
    acc.y += val.x * w.y + val.y * w.x;
  }
  lC[t] = acc;
  __syncthreads();
  float r = 0.f;
  for (int pp = 0; pp < 16; ++pp) {
    float2 val = lC[pp * 16 + q];
    float2 w = tw[(p * pp) & 15];
    r += val.x * w.x - val.y * w.y;
  }
  r *= (1.f / 400.f);
  int n = c * 256 + t;
  ms[(size_t)n * KOUT + uv] = __float2bfloat16(r);
}

// zero the k in [400,416) pad of the m plane (hi only)
__global__ void pad_m(__hip_bfloat16* __restrict__ ms) {
  int idx = blockIdx.x * 256 + threadIdx.x;   // 4096*16
  int n = idx >> 4;
  int k = 400 + (idx & 15);
  ms[(size_t)n * KOUT + k] = __float2bfloat16(0.f);
}

// convert x (8192x400 f32) to bf16 padded [8192][KOUT] (hi only)
__global__ void prep_x(const float* __restrict__ x, __hip_bfloat16* __restrict__ xs) {
  int idx = blockIdx.x * 256 + threadIdx.x;   // 8192*52
  if (idx >= 8192 * 52) return;
  int b = idx / 52, c8 = idx % 52;
  int k = c8 * 8;
  short8 hh = {};
  if (k < 400) {
    const float4* xp = (const float4*)(x + (size_t)b * 400 + k);
    float4 v0 = xp[0], v1 = xp[1];
    float vals[8] = {v0.x, v0.y, v0.z, v0.w, v1.x, v1.y, v1.z, v1.w};
#pragma unroll
    for (int i = 0; i < 8; ++i) hh[i] = braw(__float2bfloat16(vals[i]));
  }
  *(short8*)(xs + (size_t)b * KOUT + k) = hh;
}

// ---------------- Stage 5: output GEMM, x bf16 x m bf16, 128x128 tile ----------------
__global__ __launch_bounds__(512, 2) void out_mfma(
    const __hip_bfloat16* __restrict__ xs, const __hip_bfloat16* __restrict__ ms,
    float* __restrict__ Y) {
  __shared__ char lds[2][16384];   // A @0 (8192), B @8192
  const int t = threadIdx.x;
  const int lane = t & 63;
  const int wid = t >> 6;
  const int wm = wid >> 2, wn = wid & 3;
  const int rowBase = blockIdx.y * 128, colBase = blockIdx.x * 128;

  size_t gA1, gB1;
  int ldsA1, ldsB1;
  {
    int cid = t;                          // 0..511
    int r = (cid >> 2) & 127, cp = cid & 3;
    int cg = cp ^ ((r >> 1) & 3);
    gA1 = (size_t)(rowBase + r) * KOUT + cg * 8;
    gB1 = (size_t)(colBase + r) * KOUT + cg * 8;
    ldsA1 = cid * 16;
    ldsB1 = 8192 + cid * 16;
  }
  int aoff[4], boff[2];
#pragma unroll
  for (int mi = 0; mi < 4; ++mi) {
    int ra = wm * 64 + mi * 16 + (lane & 15);
    int ch = (lane >> 4) ^ ((ra >> 1) & 3);
    aoff[mi] = (ra * 4 + ch) * 16;
  }
#pragma unroll
  for (int ni = 0; ni < 2; ++ni) {
    int cb = wn * 32 + ni * 16 + (lane & 15);
    int ch = (lane >> 4) ^ ((cb >> 1) & 3);
    boff[ni] = 8192 + (cb * 4 + ch) * 16;
  }

  f32x4 acc[4][2] = {};

  gld16(xs + gA1, &lds[0][ldsA1]);
  gld16(ms + gB1, &lds[0][ldsB1]);

#pragma unroll 1
  for (int ks = 0; ks < 13; ++ks) {
    int cur = ks & 1;
    int k1 = (ks + 1) * 32;
    asm volatile("s_waitcnt vmcnt(0)" ::: "memory");
    __builtin_amdgcn_sched_barrier(0);
    __builtin_amdgcn_s_barrier();
    __builtin_amdgcn_sched_barrier(0);
    short8 bh[2];
#pragma unroll
    for (int ni = 0; ni < 2; ++ni)
      bh[ni] = *(const short8*)(&lds[cur][boff[ni]]);
#pragma unroll
    for (int mi = 0; mi < 4; ++mi) {
      short8 ah = *(const short8*)(&lds[cur][aoff[mi]]);
      if (ks < 12) {
        if (mi == 0) gld16(xs + gA1 + k1, &lds[cur ^ 1][ldsA1]);
        else if (mi == 1) gld16(ms + gB1 + k1, &lds[cur ^ 1][ldsB1]);
      }
      __builtin_amdgcn_s_setprio(1);
#pragma unroll
      for (int ni = 0; ni < 2; ++ni)
        acc[mi][ni] = MFMA16(ah, bh[ni], acc[mi][ni]);
      __builtin_amdgcn_s_setprio(0);
    }
    __builtin_amdgcn_sched_barrier(0);
  }

#pragma unroll
  for (int mi = 0; mi < 4; ++mi)
#pragma unroll
    for (int ni = 0; ni < 2; ++ni) {
      int rb = rowBase + wm * 64 + mi * 16 + (lane >> 4) * 4;
      int cc = colBase + wn * 32 + ni * 16 + (lane & 15);
#pragma unroll
      for (int j = 0; j < 4; ++j)
        Y[(size_t)(rb + j) * 4096 + cc] = acc[mi][ni][j];
    }
}

// ---------------- Launcher ----------------
extern "C" void kernel_launch(void* const* d_in, const int* in_sizes, int n_in,
                              void* d_out, int out_size, void* d_ws, size_t ws_size,
                              hipStream_t stream) {
  const float* x = (const float*)d_in[0];     // (8192,1,20,20)
  const float* sig = (const float*)d_in[1];   // (16,2,24,24)
  float* out = (float*)d_out;                 // (8192,16,16,16)
  char* ws = (char*)d_ws;

  const size_t specBytes = 32ull * 576 * sizeof(float2);
  const size_t xsBytes = XPL * 2;                       // one bf16 plane
  const size_t msBytes = MPL * 2;                       // one bf16 plane
  const size_t fixed = specBytes + xsBytes + msBytes;
  const size_t setB = SETSTR * 2;                       // bytes per split set
  const size_t perCh = 5 * setB + (size_t)MAPSZ * 8;    // 5 rotating sets + P0

  int cg = 1;
  if (ws_size > fixed) {
    size_t av = (ws_size - fixed) / perCh;
    cg = (av < 1) ? 1 : (av > 16 ? 16 : (int)av);
  }

  float2* spec = (float2*)ws;
  __hip_bfloat16* xs = (__hip_bfloat16*)(ws + specBytes);
  __hip_bfloat16* ms = (__hip_bfloat16*)(ws + specBytes + xsBytes);
  __hip_bfloat16* S0 = (__hip_bfloat16*)(ws + fixed);          // X -> T16
  __hip_bfloat16* S1 = S0 + (size_t)cg * SETSTR;               // XT -> T4
  __hip_bfloat16* S2 = S1 + (size_t)cg * SETSTR;               // X2 -> T8
  __hip_bfloat16* S3 = S2 + (size_t)cg * SETSTR;               // X2T -> T4T
  __hip_bfloat16* S4 = S3 + (size_t)cg * SETSTR;               // CT -> T8T
  float2* P0 = (float2*)(S4 + (size_t)cg * SETSTR);

  spectrum_kernel<<<dim3(32), dim3(576), 0, stream>>>(sig, spec);
  prep_x<<<dim3((8192 * 52 + 255) / 256), dim3(256), 0, stream>>>(x, xs);
  pad_m<<<dim3(256), dim3(256), 0, stream>>>(ms);

  const float scale = 1.f / 4.f;  // s = 2 squarings, Paterson-Stockmeyer order 4
  for (int c0 = 0; c0 < 16; c0 += cg) {
    int g = (16 - c0 < cg) ? (16 - c0) : cg;
    buildBX<<<dim3(1296, g), dim3(256), 0, stream>>>(spec, S0, c0, scale);
    transpose4<<<dim3(9, 9, g), dim3(256), 0, stream>>>(S0, S1);
    // X2 = X*X  (and X2T)
    cgemm_mfma<<<dim3(15 * g), dim3(512), 0, stream>>>(S0, S1, S2, S3, nullptr,
                                                       1.f, 0.f, 3);
    // CT = I/2 + XT/6 + X2T/24
    buildC<<<dim3(1296, g), dim3(256), 0, stream>>>(S1, S3, S4);
    // T4 = X2*C + I + X  (and T4T)
    cgemm_mfma<<<dim3(15 * g), dim3(512), 0, stream>>>(S2, S4, S1, S3, S0,
                                                       1.f, 1.f, 3);
    // T8 = T4*T4 (and T8T)
    cgemm_mfma<<<dim3(15 * g), dim3(512), 0, stream>>>(S1, S3, S2, S4, nullptr,
                                                       1.f, 0.f, 3);
    // T16 = T8*T8 (row-major only; feeds passAB)
    cgemm_mfma<<<dim3(15 * g), dim3(512), 0, stream>>>(S2, S4, S0, S3, nullptr,
                                                       1.f, 0.f, 1);
    passAB<<<dim3(256, g), dim3(448), 0, stream>>>(S0, P0);
    passCD<<<dim3(400, g), dim3(256), 0, stream>>>(P0, ms, c0);
  }

  out_mfma<<<dim3(32, 64), dim3(512), 0, stream>>>(xs, ms, out);
}